// Round 1
// baseline (223.876 us; speedup 1.0000x reference)
//
#include <hip/hip_runtime.h>
#include <hip/hip_bf16.h>
#include <cmath>

#define B_ 8
#define T_ 2048
#define D_ 1024
#define H_ 64
#define BT_ (B_*T_)

typedef __bf16 bf16x8 __attribute__((ext_vector_type(8)));
typedef float f32x4 __attribute__((ext_vector_type(4)));

// ---------------------------------------------------------------------------
// Kernel 1: cast + transpose weights: Wt[mat][h=64][d=1024] bf16
// mat order: 0=q, 1=k, 2=v
// ---------------------------------------------------------------------------
__global__ __launch_bounds__(256)
void castw_kernel(const float* __restrict__ w0,
                  const float* __restrict__ w1,
                  const float* __restrict__ w2,
                  __bf16* __restrict__ Wt) {
  int idx = blockIdx.x * 256 + threadIdx.x;     // 3*65536 total
  int mat = idx >> 16;
  int rem = idx & 65535;
  int d = rem >> 6, h = rem & 63;
  const float* w = (mat == 0) ? w0 : (mat == 1) ? w1 : w2;
  Wt[mat * 65536 + h * 1024 + d] = (__bf16)w[rem];  // read coalesced over h
}

// ---------------------------------------------------------------------------
// Kernel 2: fused QKV projection (bf16 MFMA, fp32 accumulate)
// grid (256, 3), block 256 (4 waves x 16 rows = 64 rows/block)
// q,k stored row-major [t][h]; v stored transposed [h][t] for PV B-operand.
// ---------------------------------------------------------------------------
__global__ __launch_bounds__(256)
void proj_kernel(const float* __restrict__ x,
                 const __bf16* __restrict__ Wt,
                 const float* __restrict__ bq,
                 const float* __restrict__ bk,
                 const float* __restrict__ bv,
                 __bf16* __restrict__ qb,
                 __bf16* __restrict__ kb,
                 __bf16* __restrict__ vt) {
  const int tid  = threadIdx.x;
  const int wv   = tid >> 6;
  const int lane = tid & 63;
  const int ln   = lane & 15;
  const int quad = lane >> 4;
  const int m0   = blockIdx.x * 64 + wv * 16;
  const int mat  = blockIdx.y;

  const __bf16* W    = Wt + mat * 65536;
  const float*  bias = (mat == 0) ? bq : (mat == 1) ? bk : bv;

  f32x4 acc[4] = {};
  const float* xrow = x + (size_t)(m0 + ln) * D_ + quad * 8;

  for (int kt = 0; kt < D_; kt += 32) {
    float4 f0 = *(const float4*)(xrow + kt);
    float4 f1 = *(const float4*)(xrow + kt + 4);
    bf16x8 a;
    a[0] = (__bf16)f0.x; a[1] = (__bf16)f0.y; a[2] = (__bf16)f0.z; a[3] = (__bf16)f0.w;
    a[4] = (__bf16)f1.x; a[5] = (__bf16)f1.y; a[6] = (__bf16)f1.z; a[7] = (__bf16)f1.w;
#pragma unroll
    for (int nt = 0; nt < 4; nt++) {
      bf16x8 bfr = *(const bf16x8*)(W + (nt * 16 + ln) * 1024 + kt + quad * 8);
      acc[nt] = __builtin_amdgcn_mfma_f32_16x16x32_bf16(a, bfr, acc[nt], 0, 0, 0);
    }
  }

#pragma unroll
  for (int nt = 0; nt < 4; nt++) {
    int col = nt * 16 + ln;
    float bcol = bias[col];
#pragma unroll
    for (int r = 0; r < 4; r++) {
      int grow = m0 + quad * 4 + r;       // global row = b*T + t
      float val = acc[nt][r] + bcol;
      if (mat == 2) {
        int bb = grow >> 11, t = grow & 2047;
        vt[((size_t)(bb * 64 + col)) * T_ + t] = (__bf16)val;
      } else if (mat == 0) {
        qb[(size_t)grow * 64 + col] = (__bf16)val;
      } else {
        kb[(size_t)grow * 64 + col] = (__bf16)val;
      }
    }
  }
}

// ---------------------------------------------------------------------------
// Kernel 3: causal flash attention.
// grid (T/16=128, B=8), block 256. All 4 waves share one 16-row q-tile,
// splitting the kv tiles (width 32) round-robin; merged at the end via LDS.
// ---------------------------------------------------------------------------
__global__ __launch_bounds__(256)
void attn_kernel(const __bf16* __restrict__ qb,
                 const __bf16* __restrict__ kb,
                 const __bf16* __restrict__ vt,
                 float* __restrict__ out) {
  __shared__ __align__(16) __bf16 pA[4][16][40];   // stride 40 -> bank spread
  __shared__ float ml_m[4][16];
  __shared__ float ml_l[4][16];
  __shared__ float olds[4][16][64];

  const int tid   = threadIdx.x;
  const int wv    = tid >> 6;
  const int lane  = tid & 63;
  const int ln    = lane & 15;
  const int quad  = lane >> 4;
  const int qbase = blockIdx.x * 16;
  const int b     = blockIdx.y;

  const __bf16* Q = qb + (size_t)b * T_ * 64;
  const __bf16* K = kb + (size_t)b * T_ * 64;
  const __bf16* V = vt + (size_t)b * 64 * T_;

  // Q A-frags for the two 32-wide k-steps of head dim 64
  bf16x8 qa0 = *(const bf16x8*)(Q + (qbase + ln) * 64 + quad * 8);
  bf16x8 qa1 = *(const bf16x8*)(Q + (qbase + ln) * 64 + 32 + quad * 8);

  f32x4 acc[4] = {};
  float m_i[4], l_i[4];
#pragma unroll
  for (int r = 0; r < 4; r++) { m_i[r] = -INFINITY; l_i[r] = 0.f; }

  const int ntiles = (qbase + 16 + 31) >> 5;   // ceil((qbase+16)/32)
  const float scale = 0.125f;                  // 1/sqrt(64)

  for (int jt = wv; jt < ntiles; jt += 4) {
    const int kv0 = jt * 32;

    // S = Q K^T for 16 q-rows x 32 kv-cols (two 16-wide halves)
    f32x4 s0 = {}, s1 = {};
    {
      bf16x8 k00 = *(const bf16x8*)(K + (kv0 + ln) * 64 + quad * 8);
      bf16x8 k01 = *(const bf16x8*)(K + (kv0 + ln) * 64 + 32 + quad * 8);
      s0 = __builtin_amdgcn_mfma_f32_16x16x32_bf16(qa0, k00, s0, 0, 0, 0);
      s0 = __builtin_amdgcn_mfma_f32_16x16x32_bf16(qa1, k01, s0, 0, 0, 0);
      bf16x8 k10 = *(const bf16x8*)(K + (kv0 + 16 + ln) * 64 + quad * 8);
      bf16x8 k11 = *(const bf16x8*)(K + (kv0 + 16 + ln) * 64 + 32 + quad * 8);
      s1 = __builtin_amdgcn_mfma_f32_16x16x32_bf16(qa0, k10, s1, 0, 0, 0);
      s1 = __builtin_amdgcn_mfma_f32_16x16x32_bf16(qa1, k11, s1, 0, 0, 0);
    }

    // mask + scale; C-layout: row=(quad*4+r) within tile, col=ln (+16 for s1)
    const int col0 = kv0 + ln, col1 = kv0 + 16 + ln;
    float p0[4], p1[4], mx[4];
#pragma unroll
    for (int r = 0; r < 4; r++) {
      int row = qbase + quad * 4 + r;
      float v0 = (col0 <= row) ? s0[r] * scale : -INFINITY;
      float v1 = (col1 <= row) ? s1[r] * scale : -INFINITY;
      p0[r] = v0; p1[r] = v1;
      mx[r] = fmaxf(v0, v1);
    }
    // rowmax across the 16 lanes of each quad
#pragma unroll
    for (int off = 1; off < 16; off <<= 1) {
#pragma unroll
      for (int r = 0; r < 4; r++)
        mx[r] = fmaxf(mx[r], __shfl_xor(mx[r], off));
    }
    float alpha[4], sm[4];
#pragma unroll
    for (int r = 0; r < 4; r++) {
      float mnew = fmaxf(m_i[r], mx[r]);
      alpha[r] = __expf(m_i[r] - mnew);
      m_i[r] = mnew;
      p0[r] = __expf(p0[r] - mnew);
      p1[r] = __expf(p1[r] - mnew);
      sm[r] = p0[r] + p1[r];
    }
#pragma unroll
    for (int off = 1; off < 16; off <<= 1) {
#pragma unroll
      for (int r = 0; r < 4; r++)
        sm[r] += __shfl_xor(sm[r], off);
    }
#pragma unroll
    for (int r = 0; r < 4; r++) {
      l_i[r] = l_i[r] * alpha[r] + sm[r];
#pragma unroll
      for (int nt = 0; nt < 4; nt++)
        acc[nt][r] *= alpha[r];
      pA[wv][quad * 4 + r][ln]      = (__bf16)p0[r];
      pA[wv][quad * 4 + r][16 + ln] = (__bf16)p1[r];
    }

    // P: C-layout -> A-layout via per-wave LDS round-trip (m120 pattern)
    bf16x8 pa = *(const bf16x8*)(&pA[wv][ln][quad * 8]);
#pragma unroll
    for (int nt = 0; nt < 4; nt++) {
      bf16x8 vb = *(const bf16x8*)(V + (size_t)(nt * 16 + ln) * T_ + kv0 + quad * 8);
      acc[nt] = __builtin_amdgcn_mfma_f32_16x16x32_bf16(pa, vb, acc[nt], 0, 0, 0);
    }
  }

  // --- merge the 4 waves' partial (m, l, O) ---
  if (ln == 0) {
#pragma unroll
    for (int r = 0; r < 4; r++) {
      ml_m[wv][quad * 4 + r] = m_i[r];
      ml_l[wv][quad * 4 + r] = l_i[r];
    }
  }
  __syncthreads();

#pragma unroll
  for (int r = 0; r < 4; r++) {
    int row = quad * 4 + r;
    float mstar = fmaxf(fmaxf(ml_m[0][row], ml_m[1][row]),
                        fmaxf(ml_m[2][row], ml_m[3][row]));
    float factor = __expf(m_i[r] - mstar);   // 0 for waves with no tiles
#pragma unroll
    for (int nt = 0; nt < 4; nt++)
      olds[wv][row][nt * 16 + ln] = acc[nt][r] * factor;
  }
  __syncthreads();

  {
    int row = tid >> 4;
    int h0 = (tid & 15) * 4;
    float mstar = fmaxf(fmaxf(ml_m[0][row], ml_m[1][row]),
                        fmaxf(ml_m[2][row], ml_m[3][row]));
    float ltot = 0.f;
#pragma unroll
    for (int w = 0; w < 4; w++)
      ltot += ml_l[w][row] * __expf(ml_m[w][row] - mstar);
    float inv = 1.0f / ltot;
    float4 o = {0.f, 0.f, 0.f, 0.f};
#pragma unroll
    for (int w = 0; w < 4; w++) {
      float4 t = *(const float4*)(&olds[w][row][h0]);
      o.x += t.x; o.y += t.y; o.z += t.z; o.w += t.w;
    }
    o.x *= inv; o.y *= inv; o.z *= inv; o.w *= inv;
    *(float4*)(out + ((size_t)(b * T_ + qbase + row)) * 64 + h0) = o;
  }
}

// ---------------------------------------------------------------------------
extern "C" void kernel_launch(void* const* d_in, const int* in_sizes, int n_in,
                              void* d_out, int out_size, void* d_ws, size_t ws_size,
                              hipStream_t stream) {
  const float* x  = (const float*)d_in[0];
  const float* Wk = (const float*)d_in[1];
  const float* bk = (const float*)d_in[2];
  const float* Wq = (const float*)d_in[3];
  const float* bq = (const float*)d_in[4];
  const float* Wv = (const float*)d_in[5];
  const float* bv = (const float*)d_in[6];
  float* out = (float*)d_out;

  char* ws = (char*)d_ws;
  __bf16* qb = (__bf16*)(ws);                                  // 2 MB
  __bf16* kb = (__bf16*)(ws + (size_t)2 * 1024 * 1024);        // 2 MB
  __bf16* vt = (__bf16*)(ws + (size_t)4 * 1024 * 1024);        // 2 MB (transposed)
  __bf16* Wt = (__bf16*)(ws + (size_t)6 * 1024 * 1024);        // 384 KB

  castw_kernel<<<768, 256, 0, stream>>>(Wq, Wk, Wv, Wt);
  proj_kernel<<<dim3(256, 3), 256, 0, stream>>>(x, Wt, bq, bk, bv, qb, kb, vt);
  attn_kernel<<<dim3(128, 8), 256, 0, stream>>>(qb, kb, vt, out);
}

// Round 2
// 212.546 us; speedup vs baseline: 1.0533x; 1.0533x over previous
//
#include <hip/hip_runtime.h>
#include <hip/hip_bf16.h>
#include <cmath>

#define B_ 8
#define T_ 2048
#define D_ 1024
#define H_ 64

typedef __bf16 bf16x8 __attribute__((ext_vector_type(8)));
typedef __bf16 bf16x4 __attribute__((ext_vector_type(4)));
typedef float f32x4 __attribute__((ext_vector_type(4)));

// ---------------------------------------------------------------------------
// Kernel 1: cast + transpose weights via LDS: Wt[mat][h=64][d=1024] bf16
// mat order: 0=q, 1=k, 2=v. grid (16, 3), block 256.
// Coalesced fp32 reads, coalesced 32B bf16 writes (v1 did 2B scattered writes
// -> ~74 us; this should be ~3 us).
// ---------------------------------------------------------------------------
__global__ __launch_bounds__(256)
void castw_kernel(const float* __restrict__ w0,
                  const float* __restrict__ w1,
                  const float* __restrict__ w2,
                  __bf16* __restrict__ Wt) {
  __shared__ float tile[64][65];
  const int mat = blockIdx.y;
  const float* w = (mat == 0) ? w0 : (mat == 1) ? w1 : w2;
  const int d0 = blockIdx.x * 64;
  const int t = threadIdx.x;
#pragma unroll
  for (int i = 0; i < 16; i++) {
    int idx = i * 256 + t;
    int dl = idx >> 6, h = idx & 63;
    tile[dl][h] = w[(size_t)(d0 + dl) * 64 + h];   // coalesced over h
  }
  __syncthreads();
  const int h = t >> 2;
  const int dc = (t & 3) * 16;
  bf16x8 o0, o1;
#pragma unroll
  for (int j = 0; j < 8; j++) {
    o0[j] = (__bf16)tile[dc + j][h];
    o1[j] = (__bf16)tile[dc + 8 + j][h];
  }
  bf16x8* dst = (bf16x8*)(Wt + (size_t)mat * 65536 + (size_t)h * 1024 + d0 + dc);
  dst[0] = o0;
  dst[1] = o1;
}

// ---------------------------------------------------------------------------
// Kernel 2: fused QKV projection. grid 512, block 256.
// Block covers 32 rows x all 192 cols; wave = (mtile = wv>>1, khalf = wv&1):
// 16 rows x 12 N-tiles x K=512. x read+converted ONCE (was 3x), 12 MFMAs per
// A-frag load (was 4). K-split keeps 2048 waves (8/CU) for HBM latency hiding.
// K-halves combined through LDS; khalf==0 waves run the epilogue.
// ---------------------------------------------------------------------------
__global__ __launch_bounds__(256)
void proj_kernel(const float* __restrict__ x,
                 const __bf16* __restrict__ Wt,
                 const float* __restrict__ bq,
                 const float* __restrict__ bk,
                 const float* __restrict__ bv,
                 __bf16* __restrict__ qb,
                 __bf16* __restrict__ kb,
                 __bf16* __restrict__ vt) {
  __shared__ float red[2][64][48];   // [mtile][lane][nt*4+r]

  const int tid   = threadIdx.x;
  const int wv    = tid >> 6;
  const int lane  = tid & 63;
  const int ln    = lane & 15;
  const int quad  = lane >> 4;
  const int mtile = wv >> 1;
  const int khalf = wv & 1;
  const int m0    = blockIdx.x * 32 + mtile * 16;
  const int k0    = khalf * 512;

  f32x4 acc[12] = {};
  const float*  xrow  = x  + (size_t)(m0 + ln) * D_ + k0 + quad * 8;
  const __bf16* wbase = Wt + (size_t)ln * 1024 + k0 + quad * 8;

  for (int kt = 0; kt < 512; kt += 32) {
    float4 f0 = *(const float4*)(xrow + kt);
    float4 f1 = *(const float4*)(xrow + kt + 4);
    bf16x8 a;
    a[0] = (__bf16)f0.x; a[1] = (__bf16)f0.y; a[2] = (__bf16)f0.z; a[3] = (__bf16)f0.w;
    a[4] = (__bf16)f1.x; a[5] = (__bf16)f1.y; a[6] = (__bf16)f1.z; a[7] = (__bf16)f1.w;
#pragma unroll
    for (int nt = 0; nt < 12; nt++) {
      bf16x8 bfr = *(const bf16x8*)(wbase + (size_t)nt * 16 * 1024 + kt);
      acc[nt] = __builtin_amdgcn_mfma_f32_16x16x32_bf16(a, bfr, acc[nt], 0, 0, 0);
    }
  }

  if (khalf == 1) {
#pragma unroll
    for (int nt = 0; nt < 12; nt++)
      *(f32x4*)(&red[mtile][lane][nt * 4]) = acc[nt];
  }
  __syncthreads();

  if (khalf == 0) {
#pragma unroll
    for (int nt = 0; nt < 12; nt++) {
      f32x4 other = *(const f32x4*)(&red[mtile][lane][nt * 4]);
      int col = nt * 16 + ln;
      int mat = nt >> 2;          // 0..3 -> q, 4..7 -> k, 8..11 -> v
      int h = col & 63;
      float bcol = ((mat == 0) ? bq : (mat == 1) ? bk : bv)[h];
      if (mat < 2) {
        __bf16* dst = (mat == 0) ? qb : kb;
#pragma unroll
        for (int r = 0; r < 4; r++) {
          int grow = m0 + quad * 4 + r;
          dst[(size_t)grow * 64 + h] = (__bf16)(acc[nt][r] + other[r] + bcol);
        }
      } else {
        int grow0 = m0 + quad * 4;
        int bb = grow0 >> 11, t0 = grow0 & 2047;
        bf16x4 pv;
#pragma unroll
        for (int r = 0; r < 4; r++)
          pv[r] = (__bf16)(acc[nt][r] + other[r] + bcol);
        *(bf16x4*)(vt + (size_t)(bb * 64 + h) * T_ + t0) = pv;  // 8B stores
      }
    }
  }
}

// ---------------------------------------------------------------------------
// Kernel 3: causal flash attention, 64-wide kv tiles (softmax overhead per kv
// element halved vs v1's 32-wide). grid (128, 8), block 256; 4 waves share one
// 16-row q-tile, round-robin over kv tiles, merged at the end via LDS.
// ---------------------------------------------------------------------------
__global__ __launch_bounds__(256)
void attn_kernel(const __bf16* __restrict__ qb,
                 const __bf16* __restrict__ kb,
                 const __bf16* __restrict__ vt,
                 float* __restrict__ out) {
  __shared__ __align__(16) __bf16 pA[4][16][72];  // 144B row stride: 16B-aligned, bank-balanced
  __shared__ float ml_m[4][16];
  __shared__ float ml_l[4][16];
  __shared__ float olds[4][16][64];

  const int tid   = threadIdx.x;
  const int wv    = tid >> 6;
  const int lane  = tid & 63;
  const int ln    = lane & 15;
  const int quad  = lane >> 4;
  const int qbase = blockIdx.x * 16;
  const int b     = blockIdx.y;

  const __bf16* Q = qb + (size_t)b * T_ * 64;
  const __bf16* K = kb + (size_t)b * T_ * 64;
  const __bf16* V = vt + (size_t)b * 64 * T_;

  bf16x8 qa0 = *(const bf16x8*)(Q + (qbase + ln) * 64 + quad * 8);
  bf16x8 qa1 = *(const bf16x8*)(Q + (qbase + ln) * 64 + 32 + quad * 8);

  f32x4 acc[4] = {};
  float m_i[4], l_i[4];
#pragma unroll
  for (int r = 0; r < 4; r++) { m_i[r] = -INFINITY; l_i[r] = 0.f; }

  const int ntiles = (qbase + 16 + 63) >> 6;   // ceil((qbase+16)/64)
  const float scale = 0.125f;                  // 1/sqrt(64)

  for (int jt = wv; jt < ntiles; jt += 4) {
    const int kv0 = jt * 64;

    // S = Q K^T: 16 q-rows x 64 kv-cols (four 16-wide halves, K-dim 64 = 2 steps)
    f32x4 s[4] = {};
#pragma unroll
    for (int h = 0; h < 4; h++) {
      const __bf16* kr = K + (size_t)(kv0 + h * 16 + ln) * 64 + quad * 8;
      s[h] = __builtin_amdgcn_mfma_f32_16x16x32_bf16(qa0, *(const bf16x8*)kr, s[h], 0, 0, 0);
      s[h] = __builtin_amdgcn_mfma_f32_16x16x32_bf16(qa1, *(const bf16x8*)(kr + 32), s[h], 0, 0, 0);
    }

    // mask + scale; C-layout: row=(quad*4+r), col = kv0 + h*16 + ln
    float p[4][4], mx[4];
#pragma unroll
    for (int r = 0; r < 4; r++) {
      int row = qbase + quad * 4 + r;
      mx[r] = -INFINITY;
#pragma unroll
      for (int h = 0; h < 4; h++) {
        int col = kv0 + h * 16 + ln;
        float v = (col <= row) ? s[h][r] * scale : -INFINITY;
        p[h][r] = v;
        mx[r] = fmaxf(mx[r], v);
      }
    }
#pragma unroll
    for (int off = 1; off < 16; off <<= 1)
#pragma unroll
      for (int r = 0; r < 4; r++)
        mx[r] = fmaxf(mx[r], __shfl_xor(mx[r], off));

    float alpha[4], sm[4];
#pragma unroll
    for (int r = 0; r < 4; r++) {
      float mnew = fmaxf(m_i[r], mx[r]);
      alpha[r] = __expf(m_i[r] - mnew);
      m_i[r] = mnew;
      sm[r] = 0.f;
#pragma unroll
      for (int h = 0; h < 4; h++) {
        p[h][r] = __expf(p[h][r] - mnew);
        sm[r] += p[h][r];
      }
    }
#pragma unroll
    for (int off = 1; off < 16; off <<= 1)
#pragma unroll
      for (int r = 0; r < 4; r++)
        sm[r] += __shfl_xor(sm[r], off);

#pragma unroll
    for (int r = 0; r < 4; r++) {
      l_i[r] = l_i[r] * alpha[r] + sm[r];
#pragma unroll
      for (int nt = 0; nt < 4; nt++)
        acc[nt][r] *= alpha[r];
#pragma unroll
      for (int h = 0; h < 4; h++)
        pA[wv][quad * 4 + r][h * 16 + ln] = (__bf16)p[h][r];
    }

    // P: C-layout -> A-layout via per-wave LDS round-trip (m120 pattern)
    bf16x8 pa0 = *(const bf16x8*)(&pA[wv][ln][quad * 8]);
    bf16x8 pa1 = *(const bf16x8*)(&pA[wv][ln][32 + quad * 8]);
#pragma unroll
    for (int nt = 0; nt < 4; nt++) {
      const __bf16* vr = V + (size_t)(nt * 16 + ln) * T_ + kv0 + quad * 8;
      acc[nt] = __builtin_amdgcn_mfma_f32_16x16x32_bf16(pa0, *(const bf16x8*)vr, acc[nt], 0, 0, 0);
      acc[nt] = __builtin_amdgcn_mfma_f32_16x16x32_bf16(pa1, *(const bf16x8*)(vr + 32), acc[nt], 0, 0, 0);
    }
  }

  // --- merge the 4 waves' partial (m, l, O) ---
  if (ln == 0) {
#pragma unroll
    for (int r = 0; r < 4; r++) {
      ml_m[wv][quad * 4 + r] = m_i[r];
      ml_l[wv][quad * 4 + r] = l_i[r];
    }
  }
  __syncthreads();

#pragma unroll
  for (int r = 0; r < 4; r++) {
    int row = quad * 4 + r;
    float mstar = fmaxf(fmaxf(ml_m[0][row], ml_m[1][row]),
                        fmaxf(ml_m[2][row], ml_m[3][row]));
    float factor = __expf(m_i[r] - mstar);   // 0 for waves with no tiles
#pragma unroll
    for (int nt = 0; nt < 4; nt++)
      olds[wv][row][nt * 16 + ln] = acc[nt][r] * factor;
  }
  __syncthreads();

  {
    int row = tid >> 4;
    int h0 = (tid & 15) * 4;
    float mstar = fmaxf(fmaxf(ml_m[0][row], ml_m[1][row]),
                        fmaxf(ml_m[2][row], ml_m[3][row]));
    float ltot = 0.f;
#pragma unroll
    for (int w = 0; w < 4; w++)
      ltot += ml_l[w][row] * __expf(ml_m[w][row] - mstar);
    float inv = 1.0f / ltot;
    float4 o = {0.f, 0.f, 0.f, 0.f};
#pragma unroll
    for (int w = 0; w < 4; w++) {
      float4 t = *(const float4*)(&olds[w][row][h0]);
      o.x += t.x; o.y += t.y; o.z += t.z; o.w += t.w;
    }
    o.x *= inv; o.y *= inv; o.z *= inv; o.w *= inv;
    *(float4*)(out + ((size_t)(b * T_ + qbase + row)) * 64 + h0) = o;
  }
}

// ---------------------------------------------------------------------------
extern "C" void kernel_launch(void* const* d_in, const int* in_sizes, int n_in,
                              void* d_out, int out_size, void* d_ws, size_t ws_size,
                              hipStream_t stream) {
  const float* x  = (const float*)d_in[0];
  const float* Wk = (const float*)d_in[1];
  const float* bk = (const float*)d_in[2];
  const float* Wq = (const float*)d_in[3];
  const float* bq = (const float*)d_in[4];
  const float* Wv = (const float*)d_in[5];
  const float* bv = (const float*)d_in[6];
  float* out = (float*)d_out;

  char* ws = (char*)d_ws;
  __bf16* qb = (__bf16*)(ws);                                  // 2 MB
  __bf16* kb = (__bf16*)(ws + (size_t)2 * 1024 * 1024);        // 2 MB
  __bf16* vt = (__bf16*)(ws + (size_t)4 * 1024 * 1024);        // 2 MB (transposed)
  __bf16* Wt = (__bf16*)(ws + (size_t)6 * 1024 * 1024);        // 384 KB

  castw_kernel<<<dim3(16, 3), 256, 0, stream>>>(Wq, Wk, Wv, Wt);
  proj_kernel<<<512, 256, 0, stream>>>(x, Wt, bq, bk, bv, qb, kb, vt);
  attn_kernel<<<dim3(128, 8), 256, 0, stream>>>(qb, kb, vt, out);
}

// Round 3
// 208.958 us; speedup vs baseline: 1.0714x; 1.0172x over previous
//
#include <hip/hip_runtime.h>
#include <hip/hip_bf16.h>
#include <cmath>

#define B_ 8
#define T_ 2048
#define D_ 1024
#define H_ 64

typedef __bf16 bf16x8 __attribute__((ext_vector_type(8)));
typedef __bf16 bf16x4 __attribute__((ext_vector_type(4)));
typedef float f32x4 __attribute__((ext_vector_type(4)));

// ---------------------------------------------------------------------------
// Kernel 1: cast + transpose weights via LDS: Wt[mat][h=64][d=1024] bf16
// mat order: 0=q, 1=k, 2=v. grid (16, 3), block 256.
// ---------------------------------------------------------------------------
__global__ __launch_bounds__(256)
void castw_kernel(const float* __restrict__ w0,
                  const float* __restrict__ w1,
                  const float* __restrict__ w2,
                  __bf16* __restrict__ Wt) {
  __shared__ float tile[64][65];
  const int mat = blockIdx.y;
  const float* w = (mat == 0) ? w0 : (mat == 1) ? w1 : w2;
  const int d0 = blockIdx.x * 64;
  const int t = threadIdx.x;
#pragma unroll
  for (int i = 0; i < 16; i++) {
    int idx = i * 256 + t;
    int dl = idx >> 6, h = idx & 63;
    tile[dl][h] = w[(size_t)(d0 + dl) * 64 + h];   // coalesced over h
  }
  __syncthreads();
  const int h = t >> 2;
  const int dc = (t & 3) * 16;
  bf16x8 o0, o1;
#pragma unroll
  for (int j = 0; j < 8; j++) {
    o0[j] = (__bf16)tile[dc + j][h];
    o1[j] = (__bf16)tile[dc + 8 + j][h];
  }
  bf16x8* dst = (bf16x8*)(Wt + (size_t)mat * 65536 + (size_t)h * 1024 + d0 + dc);
  dst[0] = o0;
  dst[1] = o1;
}

// ---------------------------------------------------------------------------
// Kernel 2: fused QKV projection, 4-way K-split. grid 1024, block 256.
// Block = one 16-row M-tile x all 192 cols. Wave wv covers K in [wv*256,
// wv*256+256): 8 K-steps of 32, fully unrolled with next-step x prefetch.
// 16 waves/CU (4 blocks/CU) vs v2's 8 -> double the latency hiding; serial
// K-steps per wave 16 -> 8. Waves 1..3 dump partials to LDS (stride 52
// floats: 16B-aligned, 52%32=20 spreads all 32 banks -> kills v2's 442K
// bank conflicts); wave 0 reduces + bias + stores.
// ---------------------------------------------------------------------------
__global__ __launch_bounds__(256, 4)
void proj_kernel(const float* __restrict__ x,
                 const __bf16* __restrict__ Wt,
                 const float* __restrict__ bq,
                 const float* __restrict__ bk,
                 const float* __restrict__ bv,
                 __bf16* __restrict__ qb,
                 __bf16* __restrict__ kb,
                 __bf16* __restrict__ vt) {
  __shared__ __align__(16) float red[3][64][52];   // 37.6 KB

  const int tid   = threadIdx.x;
  const int wv    = tid >> 6;
  const int lane  = tid & 63;
  const int ln    = lane & 15;
  const int quad  = lane >> 4;
  const int m0    = blockIdx.x * 16;
  const int k0    = wv * 256;

  f32x4 acc[12] = {};
  const float*  xrow  = x  + (size_t)(m0 + ln) * D_ + k0 + quad * 8;
  const __bf16* wbase = Wt + (size_t)ln * 1024 + k0 + quad * 8;

  float4 f0 = *(const float4*)(xrow);
  float4 f1 = *(const float4*)(xrow + 4);
#pragma unroll
  for (int it = 0; it < 8; it++) {
    float4 c0 = f0, c1 = f1;
    if (it < 7) {                       // prefetch next K-step's x
      f0 = *(const float4*)(xrow + (it + 1) * 32);
      f1 = *(const float4*)(xrow + (it + 1) * 32 + 4);
    }
    bf16x8 a;
    a[0] = (__bf16)c0.x; a[1] = (__bf16)c0.y; a[2] = (__bf16)c0.z; a[3] = (__bf16)c0.w;
    a[4] = (__bf16)c1.x; a[5] = (__bf16)c1.y; a[6] = (__bf16)c1.z; a[7] = (__bf16)c1.w;
#pragma unroll
    for (int nt = 0; nt < 12; nt++) {
      bf16x8 bfr = *(const bf16x8*)(wbase + (size_t)nt * 16 * 1024 + it * 32);
      acc[nt] = __builtin_amdgcn_mfma_f32_16x16x32_bf16(a, bfr, acc[nt], 0, 0, 0);
    }
  }

  if (wv != 0) {
#pragma unroll
    for (int nt = 0; nt < 12; nt++)
      *(f32x4*)(&red[wv - 1][lane][nt * 4]) = acc[nt];
  }
  __syncthreads();

  if (wv == 0) {
#pragma unroll
    for (int nt = 0; nt < 12; nt++) {
      f32x4 p0 = *(const f32x4*)(&red[0][lane][nt * 4]);
      f32x4 p1 = *(const f32x4*)(&red[1][lane][nt * 4]);
      f32x4 p2 = *(const f32x4*)(&red[2][lane][nt * 4]);
      int mat = nt >> 2;          // 0..3 -> q, 4..7 -> k, 8..11 -> v
      int h = (nt * 16 + ln) & 63;
      float bcol = ((mat == 0) ? bq : (mat == 1) ? bk : bv)[h];
      if (mat < 2) {
        __bf16* dst = (mat == 0) ? qb : kb;
#pragma unroll
        for (int r = 0; r < 4; r++) {
          int grow = m0 + quad * 4 + r;
          dst[(size_t)grow * 64 + h] =
              (__bf16)(acc[nt][r] + p0[r] + p1[r] + p2[r] + bcol);
        }
      } else {
        int grow0 = m0 + quad * 4;
        int bb = grow0 >> 11, t0 = grow0 & 2047;
        bf16x4 pv;
#pragma unroll
        for (int r = 0; r < 4; r++)
          pv[r] = (__bf16)(acc[nt][r] + p0[r] + p1[r] + p2[r] + bcol);
        *(bf16x4*)(vt + (size_t)(bb * 64 + h) * T_ + t0) = pv;  // 8B stores
      }
    }
  }
}

// ---------------------------------------------------------------------------
// Kernel 3: causal flash attention, 64-wide kv tiles. grid (128, 8), block
// 256; 4 waves share one 16-row q-tile, round-robin over kv tiles, merged at
// the end via LDS.  (UNCHANGED from v2 so the next profile isolates it.)
// ---------------------------------------------------------------------------
__global__ __launch_bounds__(256)
void attn_kernel(const __bf16* __restrict__ qb,
                 const __bf16* __restrict__ kb,
                 const __bf16* __restrict__ vt,
                 float* __restrict__ out) {
  __shared__ __align__(16) __bf16 pA[4][16][72];
  __shared__ float ml_m[4][16];
  __shared__ float ml_l[4][16];
  __shared__ float olds[4][16][64];

  const int tid   = threadIdx.x;
  const int wv    = tid >> 6;
  const int lane  = tid & 63;
  const int ln    = lane & 15;
  const int quad  = lane >> 4;
  const int qbase = blockIdx.x * 16;
  const int b     = blockIdx.y;

  const __bf16* Q = qb + (size_t)b * T_ * 64;
  const __bf16* K = kb + (size_t)b * T_ * 64;
  const __bf16* V = vt + (size_t)b * 64 * T_;

  bf16x8 qa0 = *(const bf16x8*)(Q + (qbase + ln) * 64 + quad * 8);
  bf16x8 qa1 = *(const bf16x8*)(Q + (qbase + ln) * 64 + 32 + quad * 8);

  f32x4 acc[4] = {};
  float m_i[4], l_i[4];
#pragma unroll
  for (int r = 0; r < 4; r++) { m_i[r] = -INFINITY; l_i[r] = 0.f; }

  const int ntiles = (qbase + 16 + 63) >> 6;   // ceil((qbase+16)/64)
  const float scale = 0.125f;                  // 1/sqrt(64)

  for (int jt = wv; jt < ntiles; jt += 4) {
    const int kv0 = jt * 64;

    f32x4 s[4] = {};
#pragma unroll
    for (int h = 0; h < 4; h++) {
      const __bf16* kr = K + (size_t)(kv0 + h * 16 + ln) * 64 + quad * 8;
      s[h] = __builtin_amdgcn_mfma_f32_16x16x32_bf16(qa0, *(const bf16x8*)kr, s[h], 0, 0, 0);
      s[h] = __builtin_amdgcn_mfma_f32_16x16x32_bf16(qa1, *(const bf16x8*)(kr + 32), s[h], 0, 0, 0);
    }

    float p[4][4], mx[4];
#pragma unroll
    for (int r = 0; r < 4; r++) {
      int row = qbase + quad * 4 + r;
      mx[r] = -INFINITY;
#pragma unroll
      for (int h = 0; h < 4; h++) {
        int col = kv0 + h * 16 + ln;
        float v = (col <= row) ? s[h][r] * scale : -INFINITY;
        p[h][r] = v;
        mx[r] = fmaxf(mx[r], v);
      }
    }
#pragma unroll
    for (int off = 1; off < 16; off <<= 1)
#pragma unroll
      for (int r = 0; r < 4; r++)
        mx[r] = fmaxf(mx[r], __shfl_xor(mx[r], off));

    float alpha[4], sm[4];
#pragma unroll
    for (int r = 0; r < 4; r++) {
      float mnew = fmaxf(m_i[r], mx[r]);
      alpha[r] = __expf(m_i[r] - mnew);
      m_i[r] = mnew;
      sm[r] = 0.f;
#pragma unroll
      for (int h = 0; h < 4; h++) {
        p[h][r] = __expf(p[h][r] - mnew);
        sm[r] += p[h][r];
      }
    }
#pragma unroll
    for (int off = 1; off < 16; off <<= 1)
#pragma unroll
      for (int r = 0; r < 4; r++)
        sm[r] += __shfl_xor(sm[r], off);

#pragma unroll
    for (int r = 0; r < 4; r++) {
      l_i[r] = l_i[r] * alpha[r] + sm[r];
#pragma unroll
      for (int nt = 0; nt < 4; nt++)
        acc[nt][r] *= alpha[r];
#pragma unroll
      for (int h = 0; h < 4; h++)
        pA[wv][quad * 4 + r][h * 16 + ln] = (__bf16)p[h][r];
    }

    bf16x8 pa0 = *(const bf16x8*)(&pA[wv][ln][quad * 8]);
    bf16x8 pa1 = *(const bf16x8*)(&pA[wv][ln][32 + quad * 8]);
#pragma unroll
    for (int nt = 0; nt < 4; nt++) {
      const __bf16* vr = V + (size_t)(nt * 16 + ln) * T_ + kv0 + quad * 8;
      acc[nt] = __builtin_amdgcn_mfma_f32_16x16x32_bf16(pa0, *(const bf16x8*)vr, acc[nt], 0, 0, 0);
      acc[nt] = __builtin_amdgcn_mfma_f32_16x16x32_bf16(pa1, *(const bf16x8*)(vr + 32), acc[nt], 0, 0, 0);
    }
  }

  if (ln == 0) {
#pragma unroll
    for (int r = 0; r < 4; r++) {
      ml_m[wv][quad * 4 + r] = m_i[r];
      ml_l[wv][quad * 4 + r] = l_i[r];
    }
  }
  __syncthreads();

#pragma unroll
  for (int r = 0; r < 4; r++) {
    int row = quad * 4 + r;
    float mstar = fmaxf(fmaxf(ml_m[0][row], ml_m[1][row]),
                        fmaxf(ml_m[2][row], ml_m[3][row]));
    float factor = __expf(m_i[r] - mstar);
#pragma unroll
    for (int nt = 0; nt < 4; nt++)
      olds[wv][row][nt * 16 + ln] = acc[nt][r] * factor;
  }
  __syncthreads();

  {
    int row = tid >> 4;
    int h0 = (tid & 15) * 4;
    float mstar = fmaxf(fmaxf(ml_m[0][row], ml_m[1][row]),
                        fmaxf(ml_m[2][row], ml_m[3][row]));
    float ltot = 0.f;
#pragma unroll
    for (int w = 0; w < 4; w++)
      ltot += ml_l[w][row] * __expf(ml_m[w][row] - mstar);
    float inv = 1.0f / ltot;
    float4 o = {0.f, 0.f, 0.f, 0.f};
#pragma unroll
    for (int w = 0; w < 4; w++) {
      float4 t = *(const float4*)(&olds[w][row][h0]);
      o.x += t.x; o.y += t.y; o.z += t.z; o.w += t.w;
    }
    o.x *= inv; o.y *= inv; o.z *= inv; o.w *= inv;
    *(float4*)(out + ((size_t)(b * T_ + qbase + row)) * 64 + h0) = o;
  }
}

// ---------------------------------------------------------------------------
extern "C" void kernel_launch(void* const* d_in, const int* in_sizes, int n_in,
                              void* d_out, int out_size, void* d_ws, size_t ws_size,
                              hipStream_t stream) {
  const float* x  = (const float*)d_in[0];
  const float* Wk = (const float*)d_in[1];
  const float* bk = (const float*)d_in[2];
  const float* Wq = (const float*)d_in[3];
  const float* bq = (const float*)d_in[4];
  const float* Wv = (const float*)d_in[5];
  const float* bv = (const float*)d_in[6];
  float* out = (float*)d_out;

  char* ws = (char*)d_ws;
  __bf16* qb = (__bf16*)(ws);                                  // 2 MB
  __bf16* kb = (__bf16*)(ws + (size_t)2 * 1024 * 1024);        // 2 MB
  __bf16* vt = (__bf16*)(ws + (size_t)4 * 1024 * 1024);        // 2 MB (transposed)
  __bf16* Wt = (__bf16*)(ws + (size_t)6 * 1024 * 1024);        // 384 KB

  castw_kernel<<<dim3(16, 3), 256, 0, stream>>>(Wq, Wk, Wv, Wt);
  proj_kernel<<<1024, 256, 0, stream>>>(x, Wt, bq, bk, bv, qb, kb, vt);
  attn_kernel<<<dim3(128, 8), 256, 0, stream>>>(qb, kb, vt, out);
}

// Round 4
// 176.944 us; speedup vs baseline: 1.2652x; 1.1809x over previous
//
#include <hip/hip_runtime.h>
#include <hip/hip_bf16.h>
#include <cmath>

#define B_ 8
#define T_ 2048
#define D_ 1024
#define H_ 64

typedef __bf16 bf16x8 __attribute__((ext_vector_type(8)));
typedef __bf16 bf16x4 __attribute__((ext_vector_type(4)));
typedef float f32x4 __attribute__((ext_vector_type(4)));

// async global->LDS, 16B per lane, lands at (wave-uniform lds base) + lane*16
__device__ __forceinline__ void async_copy16(const void* g, void* lds) {
  __builtin_amdgcn_global_load_lds(
      (const __attribute__((address_space(1))) unsigned int*)g,
      (__attribute__((address_space(3))) unsigned int*)lds,
      16, 0, 0);
}

// ---------------------------------------------------------------------------
// Kernel 1: cast + transpose weights via LDS: Wt[mat][h=64][d=1024] bf16
// ---------------------------------------------------------------------------
__global__ __launch_bounds__(256)
void castw_kernel(const float* __restrict__ w0,
                  const float* __restrict__ w1,
                  const float* __restrict__ w2,
                  __bf16* __restrict__ Wt) {
  __shared__ float tile[64][65];
  const int mat = blockIdx.y;
  const float* w = (mat == 0) ? w0 : (mat == 1) ? w1 : w2;
  const int d0 = blockIdx.x * 64;
  const int t = threadIdx.x;
#pragma unroll
  for (int i = 0; i < 16; i++) {
    int idx = i * 256 + t;
    int dl = idx >> 6, h = idx & 63;
    tile[dl][h] = w[(size_t)(d0 + dl) * 64 + h];
  }
  __syncthreads();
  const int h = t >> 2;
  const int dc = (t & 3) * 16;
  bf16x8 o0, o1;
#pragma unroll
  for (int j = 0; j < 8; j++) {
    o0[j] = (__bf16)tile[dc + j][h];
    o1[j] = (__bf16)tile[dc + 8 + j][h];
  }
  bf16x8* dst = (bf16x8*)(Wt + (size_t)mat * 65536 + (size_t)h * 1024 + d0 + dc);
  dst[0] = o0;
  dst[1] = o1;
}

// ---------------------------------------------------------------------------
// Kernel 2: fused QKV projection, m97-style LDS staging.
// grid 512, block 256. Tile: M=32 rows x N=192 (all cols), K in 16 slices of
// 64. W-slice (192x64 bf16 = 24 KB) staged via async global_load_lds (loads
// in flight on vmcnt, not VGPRs -> fixes v3's serialized scatter loads).
// x-slice (32x64) loaded coalesced fp32, cvt'd, stored to LDS with a 16B-chunk
// XOR swizzle so A-frag ds_read_b128 is bank-conflict-free. Full K per block:
// no cross-wave reduction. Wave wv owns cols [wv*48, wv*48+48) x all 32 rows.
// ---------------------------------------------------------------------------
__global__ __launch_bounds__(256)
void proj_kernel(const float* __restrict__ x,
                 const __bf16* __restrict__ Wt,
                 const float* __restrict__ bq,
                 const float* __restrict__ bk,
                 const float* __restrict__ bv,
                 __bf16* __restrict__ qb,
                 __bf16* __restrict__ kb,
                 __bf16* __restrict__ vt) {
  __shared__ __align__(16) __bf16 xs[32 * 64];    // 4 KB, XOR-swizzled chunks
  __shared__ __align__(16) __bf16 wsl[192 * 64];  // 24 KB, row-major (async dst)

  const int tid  = threadIdx.x;
  const int wv   = tid >> 6;
  const int lane = tid & 63;
  const int ln   = lane & 15;
  const int quad = lane >> 4;
  const int m0   = blockIdx.x * 32;

  // x staging coords: 2 passes, each 4 rows/wave fully coalesced (256B/row)
  const int xrow0 = tid >> 4;        // 0..15 (+16 on pass 2)
  const int xc4   = tid & 15;        // float4 chunk within row

  // W staging coords (per async instr, 8 rows x 128B = 1KB)
  const int wl_row = lane >> 3;      // 0..7
  const int wl_col = (lane & 7) * 8; // element offset in row

  f32x4 acc[6] = {};                 // [mt*3 + nt]

  for (int s = 0; s < 16; s++) {
    const int k0 = s * 64;
    __syncthreads();                 // prior slice's readers done

    // ---- stage W: 6 async 1KB copies per wave (24 total) ----
#pragma unroll
    for (int j = 0; j < 6; j++) {
      int i = wv * 6 + j;            // 0..23, covers rows i*8..i*8+7
      const __bf16* gp = Wt + (size_t)(i * 8 + wl_row) * 1024 + k0 + wl_col;
      async_copy16(gp, wsl + i * 512);
    }

    // ---- stage x: coalesced fp32 -> bf16 -> swizzled LDS ----
#pragma unroll
    for (int u = 0; u < 2; u++) {
      int row = xrow0 + u * 16;
      float4 f = *(const float4*)(x + (size_t)(m0 + row) * D_ + k0 + xc4 * 4);
      bf16x4 h;
      h[0] = (__bf16)f.x; h[1] = (__bf16)f.y; h[2] = (__bf16)f.z; h[3] = (__bf16)f.w;
      int c = xc4 >> 1;                              // 16B chunk index 0..7
      int addr = row * 64 + ((c ^ (row & 7)) * 8) + (xc4 & 1) * 4;
      *(bf16x4*)(xs + addr) = h;
    }

    __syncthreads();                 // drains vmcnt (async W) + lgkm (x writes)

    // ---- compute: 12 MFMAs per wave per slice ----
#pragma unroll
    for (int ks = 0; ks < 2; ks++) {
      bf16x8 af[2];
#pragma unroll
      for (int mt = 0; mt < 2; mt++) {
        int m = mt * 16 + ln;
        af[mt] = *(const bf16x8*)(xs + m * 64 + ((ks * 4 + quad) ^ (ln & 7)) * 8);
      }
#pragma unroll
      for (int nt = 0; nt < 3; nt++) {
        int col = wv * 48 + nt * 16 + ln;
        bf16x8 bf = *(const bf16x8*)(wsl + col * 64 + ks * 32 + quad * 8);
#pragma unroll
        for (int mt = 0; mt < 2; mt++)
          acc[mt * 3 + nt] =
              __builtin_amdgcn_mfma_f32_16x16x32_bf16(af[mt], bf, acc[mt * 3 + nt], 0, 0, 0);
      }
    }
  }

  // ---- epilogue: bias + store ----
#pragma unroll
  for (int nt = 0; nt < 3; nt++) {
    int idx = wv * 48 + nt * 16;     // multiple of 16, each tile within one mat
    int mat = idx >> 6;
    int h = (idx & 63) + ln;
    float bcol = ((mat == 0) ? bq : (mat == 1) ? bk : bv)[h];
#pragma unroll
    for (int mt = 0; mt < 2; mt++) {
      f32x4 a = acc[mt * 3 + nt];
      int grow0 = m0 + mt * 16 + quad * 4;
      if (mat < 2) {
        __bf16* dst = (mat == 0) ? qb : kb;
#pragma unroll
        for (int r = 0; r < 4; r++)
          dst[(size_t)(grow0 + r) * 64 + h] = (__bf16)(a[r] + bcol);
      } else {
        int bb = grow0 >> 11, t0 = grow0 & 2047;
        bf16x4 pv;
#pragma unroll
        for (int r = 0; r < 4; r++)
          pv[r] = (__bf16)(a[r] + bcol);
        *(bf16x4*)(vt + (size_t)(bb * 64 + h) * T_ + t0) = pv;
      }
    }
  }
}

// ---------------------------------------------------------------------------
// Kernel 3: causal flash attention, 64-wide kv tiles + software pipeline:
// next tile's K loaded right after QK consumes the K regs (WAR-safe), current
// V loaded before softmax so its latency hides under the exp/shuffle chain.
// grid (128, 8), block 256; 4 waves split kv range, merged via LDS.
// ---------------------------------------------------------------------------
__global__ __launch_bounds__(256)
void attn_kernel(const __bf16* __restrict__ qb,
                 const __bf16* __restrict__ kb,
                 const __bf16* __restrict__ vt,
                 float* __restrict__ out) {
  __shared__ __align__(16) __bf16 pA[4][16][72];
  __shared__ float ml_m[4][16];
  __shared__ float ml_l[4][16];
  __shared__ float olds[4][16][64];

  const int tid   = threadIdx.x;
  const int wv    = tid >> 6;
  const int lane  = tid & 63;
  const int ln    = lane & 15;
  const int quad  = lane >> 4;
  const int qbase = blockIdx.x * 16;
  const int b     = blockIdx.y;

  const __bf16* Q = qb + (size_t)b * T_ * 64;
  const __bf16* K = kb + (size_t)b * T_ * 64;
  const __bf16* V = vt + (size_t)b * 64 * T_;

  bf16x8 qa0 = *(const bf16x8*)(Q + (qbase + ln) * 64 + quad * 8);
  bf16x8 qa1 = *(const bf16x8*)(Q + (qbase + ln) * 64 + 32 + quad * 8);

  f32x4 acc[4] = {};
  float m_i[4], l_i[4];
#pragma unroll
  for (int r = 0; r < 4; r++) { m_i[r] = -INFINITY; l_i[r] = 0.f; }

  const int ntiles = (qbase + 16 + 63) >> 6;
  const float scale = 0.125f;

  bf16x8 kfa[4], kfb[4], vfa[4], vfb[4];
  if (wv < ntiles) {
#pragma unroll
    for (int h = 0; h < 4; h++) {
      const __bf16* kr = K + (size_t)(wv * 64 + h * 16 + ln) * 64 + quad * 8;
      kfa[h] = *(const bf16x8*)kr;
      kfb[h] = *(const bf16x8*)(kr + 32);
    }
  }

  for (int jt = wv; jt < ntiles; jt += 4) {
    const int kv0 = jt * 64;

    // QK^T (consumes kfa/kfb)
    f32x4 s[4] = {};
#pragma unroll
    for (int h = 0; h < 4; h++) {
      s[h] = __builtin_amdgcn_mfma_f32_16x16x32_bf16(qa0, kfa[h], s[h], 0, 0, 0);
      s[h] = __builtin_amdgcn_mfma_f32_16x16x32_bf16(qa1, kfb[h], s[h], 0, 0, 0);
    }

    // prefetch next tile's K (regs dead after QK) — hides under softmax+PV
    if (jt + 4 < ntiles) {
#pragma unroll
      for (int h = 0; h < 4; h++) {
        const __bf16* kr = K + (size_t)(kv0 + 256 + h * 16 + ln) * 64 + quad * 8;
        kfa[h] = *(const bf16x8*)kr;
        kfb[h] = *(const bf16x8*)(kr + 32);
      }
    }
    // current tile's V — latency hides under softmax
#pragma unroll
    for (int nt = 0; nt < 4; nt++) {
      const __bf16* vr = V + (size_t)(nt * 16 + ln) * T_ + kv0 + quad * 8;
      vfa[nt] = *(const bf16x8*)vr;
      vfb[nt] = *(const bf16x8*)(vr + 32);
    }

    // mask + scale + online softmax
    float p[4][4], mx[4];
#pragma unroll
    for (int r = 0; r < 4; r++) {
      int row = qbase + quad * 4 + r;
      mx[r] = -INFINITY;
#pragma unroll
      for (int h = 0; h < 4; h++) {
        int col = kv0 + h * 16 + ln;
        float v = (col <= row) ? s[h][r] * scale : -INFINITY;
        p[h][r] = v;
        mx[r] = fmaxf(mx[r], v);
      }
    }
#pragma unroll
    for (int off = 1; off < 16; off <<= 1)
#pragma unroll
      for (int r = 0; r < 4; r++)
        mx[r] = fmaxf(mx[r], __shfl_xor(mx[r], off));

    float alpha[4], sm[4];
#pragma unroll
    for (int r = 0; r < 4; r++) {
      float mnew = fmaxf(m_i[r], mx[r]);
      alpha[r] = __expf(m_i[r] - mnew);
      m_i[r] = mnew;
      sm[r] = 0.f;
#pragma unroll
      for (int h = 0; h < 4; h++) {
        p[h][r] = __expf(p[h][r] - mnew);
        sm[r] += p[h][r];
      }
    }
#pragma unroll
    for (int off = 1; off < 16; off <<= 1)
#pragma unroll
      for (int r = 0; r < 4; r++)
        sm[r] += __shfl_xor(sm[r], off);

#pragma unroll
    for (int r = 0; r < 4; r++) {
      l_i[r] = l_i[r] * alpha[r] + sm[r];
#pragma unroll
      for (int nt = 0; nt < 4; nt++)
        acc[nt][r] *= alpha[r];
#pragma unroll
      for (int h = 0; h < 4; h++)
        pA[wv][quad * 4 + r][h * 16 + ln] = (__bf16)p[h][r];
    }

    // P: C-layout -> A-layout via per-wave LDS round-trip
    bf16x8 pa0 = *(const bf16x8*)(&pA[wv][ln][quad * 8]);
    bf16x8 pa1 = *(const bf16x8*)(&pA[wv][ln][32 + quad * 8]);
#pragma unroll
    for (int nt = 0; nt < 4; nt++) {
      acc[nt] = __builtin_amdgcn_mfma_f32_16x16x32_bf16(pa0, vfa[nt], acc[nt], 0, 0, 0);
      acc[nt] = __builtin_amdgcn_mfma_f32_16x16x32_bf16(pa1, vfb[nt], acc[nt], 0, 0, 0);
    }
  }

  // --- merge the 4 waves' partial (m, l, O) ---
  if (ln == 0) {
#pragma unroll
    for (int r = 0; r < 4; r++) {
      ml_m[wv][quad * 4 + r] = m_i[r];
      ml_l[wv][quad * 4 + r] = l_i[r];
    }
  }
  __syncthreads();

#pragma unroll
  for (int r = 0; r < 4; r++) {
    int row = quad * 4 + r;
    float mstar = fmaxf(fmaxf(ml_m[0][row], ml_m[1][row]),
                        fmaxf(ml_m[2][row], ml_m[3][row]));
    float factor = __expf(m_i[r] - mstar);
#pragma unroll
    for (int nt = 0; nt < 4; nt++)
      olds[wv][row][nt * 16 + ln] = acc[nt][r] * factor;
  }
  __syncthreads();

  {
    int row = tid >> 4;
    int h0 = (tid & 15) * 4;
    float mstar = fmaxf(fmaxf(ml_m[0][row], ml_m[1][row]),
                        fmaxf(ml_m[2][row], ml_m[3][row]));
    float ltot = 0.f;
#pragma unroll
    for (int w = 0; w < 4; w++)
      ltot += ml_l[w][row] * __expf(ml_m[w][row] - mstar);
    float inv = 1.0f / ltot;
    float4 o = {0.f, 0.f, 0.f, 0.f};
#pragma unroll
    for (int w = 0; w < 4; w++) {
      float4 t = *(const float4*)(&olds[w][row][h0]);
      o.x += t.x; o.y += t.y; o.z += t.z; o.w += t.w;
    }
    o.x *= inv; o.y *= inv; o.z *= inv; o.w *= inv;
    *(float4*)(out + ((size_t)(b * T_ + qbase + row)) * 64 + h0) = o;
  }
}

// ---------------------------------------------------------------------------
extern "C" void kernel_launch(void* const* d_in, const int* in_sizes, int n_in,
                              void* d_out, int out_size, void* d_ws, size_t ws_size,
                              hipStream_t stream) {
  const float* x  = (const float*)d_in[0];
  const float* Wk = (const float*)d_in[1];
  const float* bk = (const float*)d_in[2];
  const float* Wq = (const float*)d_in[3];
  const float* bq = (const float*)d_in[4];
  const float* Wv = (const float*)d_in[5];
  const float* bv = (const float*)d_in[6];
  float* out = (float*)d_out;

  char* ws = (char*)d_ws;
  __bf16* qb = (__bf16*)(ws);                                  // 2 MB
  __bf16* kb = (__bf16*)(ws + (size_t)2 * 1024 * 1024);        // 2 MB
  __bf16* vt = (__bf16*)(ws + (size_t)4 * 1024 * 1024);        // 2 MB (transposed)
  __bf16* Wt = (__bf16*)(ws + (size_t)6 * 1024 * 1024);        // 384 KB

  castw_kernel<<<dim3(16, 3), 256, 0, stream>>>(Wq, Wk, Wv, Wt);
  proj_kernel<<<512, 256, 0, stream>>>(x, Wt, bq, bk, bv, qb, kb, vt);
  attn_kernel<<<dim3(128, 8), 256, 0, stream>>>(qb, kb, vt, out);
}

// Round 5
// 161.505 us; speedup vs baseline: 1.3862x; 1.0956x over previous
//
#include <hip/hip_runtime.h>
#include <hip/hip_bf16.h>
#include <cmath>

#define B_ 8
#define T_ 2048
#define D_ 1024
#define H_ 64

typedef __bf16 bf16x8 __attribute__((ext_vector_type(8)));
typedef __bf16 bf16x4 __attribute__((ext_vector_type(4)));
typedef float f32x4 __attribute__((ext_vector_type(4)));

// q scaled by 1/sqrt(64) * log2(e) so softmax runs in exp2 domain (bare v_exp_f32)
#define QSCALE 0.18033688011112042f

// async global->LDS, 16B per lane, lands at (wave-uniform lds base) + lane*16
__device__ __forceinline__ void async_copy16(const void* g, void* lds) {
  __builtin_amdgcn_global_load_lds(
      (const __attribute__((address_space(1))) unsigned int*)g,
      (__attribute__((address_space(3))) unsigned int*)lds,
      16, 0, 0);
}

// ---------------------------------------------------------------------------
// Kernel 1: cast + transpose weights via LDS: Wt[mat][h=64][d=1024] bf16
// ---------------------------------------------------------------------------
__global__ __launch_bounds__(256)
void castw_kernel(const float* __restrict__ w0,
                  const float* __restrict__ w1,
                  const float* __restrict__ w2,
                  __bf16* __restrict__ Wt) {
  __shared__ float tile[64][65];
  const int mat = blockIdx.y;
  const float* w = (mat == 0) ? w0 : (mat == 1) ? w1 : w2;
  const int d0 = blockIdx.x * 64;
  const int t = threadIdx.x;
#pragma unroll
  for (int i = 0; i < 16; i++) {
    int idx = i * 256 + t;
    int dl = idx >> 6, h = idx & 63;
    tile[dl][h] = w[(size_t)(d0 + dl) * 64 + h];
  }
  __syncthreads();
  const int h = t >> 2;
  const int dc = (t & 3) * 16;
  bf16x8 o0, o1;
#pragma unroll
  for (int j = 0; j < 8; j++) {
    o0[j] = (__bf16)tile[dc + j][h];
    o1[j] = (__bf16)tile[dc + 8 + j][h];
  }
  bf16x8* dst = (bf16x8*)(Wt + (size_t)mat * 65536 + (size_t)h * 1024 + d0 + dc);
  dst[0] = o0;
  dst[1] = o1;
}

// ---------------------------------------------------------------------------
// Kernel 2: fused QKV projection, m97-style LDS staging (unchanged from v4
// except q gets QSCALE folded into its epilogue).
// ---------------------------------------------------------------------------
__global__ __launch_bounds__(256)
void proj_kernel(const float* __restrict__ x,
                 const __bf16* __restrict__ Wt,
                 const float* __restrict__ bq,
                 const float* __restrict__ bk,
                 const float* __restrict__ bv,
                 __bf16* __restrict__ qb,
                 __bf16* __restrict__ kb,
                 __bf16* __restrict__ vt) {
  __shared__ __align__(16) __bf16 xs[32 * 64];
  __shared__ __align__(16) __bf16 wsl[192 * 64];

  const int tid  = threadIdx.x;
  const int wv   = tid >> 6;
  const int lane = tid & 63;
  const int ln   = lane & 15;
  const int quad = lane >> 4;
  const int m0   = blockIdx.x * 32;

  const int xrow0 = tid >> 4;
  const int xc4   = tid & 15;
  const int wl_row = lane >> 3;
  const int wl_col = (lane & 7) * 8;

  f32x4 acc[6] = {};

  for (int s = 0; s < 16; s++) {
    const int k0 = s * 64;
    __syncthreads();

#pragma unroll
    for (int j = 0; j < 6; j++) {
      int i = wv * 6 + j;
      const __bf16* gp = Wt + (size_t)(i * 8 + wl_row) * 1024 + k0 + wl_col;
      async_copy16(gp, wsl + i * 512);
    }

#pragma unroll
    for (int u = 0; u < 2; u++) {
      int row = xrow0 + u * 16;
      float4 f = *(const float4*)(x + (size_t)(m0 + row) * D_ + k0 + xc4 * 4);
      bf16x4 h;
      h[0] = (__bf16)f.x; h[1] = (__bf16)f.y; h[2] = (__bf16)f.z; h[3] = (__bf16)f.w;
      int c = xc4 >> 1;
      int addr = row * 64 + ((c ^ (row & 7)) * 8) + (xc4 & 1) * 4;
      *(bf16x4*)(xs + addr) = h;
    }

    __syncthreads();

#pragma unroll
    for (int ks = 0; ks < 2; ks++) {
      bf16x8 af[2];
#pragma unroll
      for (int mt = 0; mt < 2; mt++) {
        int m = mt * 16 + ln;
        af[mt] = *(const bf16x8*)(xs + m * 64 + ((ks * 4 + quad) ^ (ln & 7)) * 8);
      }
#pragma unroll
      for (int nt = 0; nt < 3; nt++) {
        int col = wv * 48 + nt * 16 + ln;
        bf16x8 bf = *(const bf16x8*)(wsl + col * 64 + ks * 32 + quad * 8);
#pragma unroll
        for (int mt = 0; mt < 2; mt++)
          acc[mt * 3 + nt] =
              __builtin_amdgcn_mfma_f32_16x16x32_bf16(af[mt], bf, acc[mt * 3 + nt], 0, 0, 0);
      }
    }
  }

#pragma unroll
  for (int nt = 0; nt < 3; nt++) {
    int idx = wv * 48 + nt * 16;
    int mat = idx >> 6;
    int h = (idx & 63) + ln;
    float bcol = ((mat == 0) ? bq : (mat == 1) ? bk : bv)[h];
#pragma unroll
    for (int mt = 0; mt < 2; mt++) {
      f32x4 a = acc[mt * 3 + nt];
      int grow0 = m0 + mt * 16 + quad * 4;
      if (mat == 0) {
#pragma unroll
        for (int r = 0; r < 4; r++)
          qb[(size_t)(grow0 + r) * 64 + h] = (__bf16)((a[r] + bcol) * QSCALE);
      } else if (mat == 1) {
#pragma unroll
        for (int r = 0; r < 4; r++)
          kb[(size_t)(grow0 + r) * 64 + h] = (__bf16)(a[r] + bcol);
      } else {
        int bb = grow0 >> 11, t0 = grow0 & 2047;
        bf16x4 pv;
#pragma unroll
        for (int r = 0; r < 4; r++)
          pv[r] = (__bf16)(a[r] + bcol);
        *(bf16x4*)(vt + (size_t)(bb * 64 + h) * T_ + t0) = pv;
      }
    }
  }
}

// ---------------------------------------------------------------------------
// Kernel 3: causal flash attention, balanced + transposed-scores.
// grid (64, 8) = 512 blocks; block processes q-tile PAIR {j, 127-j} -> every
// block has exactly 33 kv-tiles (no drain tail; v4 Occupancy was 12.6% from
// triangular imbalance). Scores computed as S^T = K*Q^T so col=q-row=ln:
// row max/sum = 15 in-lane ops + 2 shuffle rounds (v4: 32 swizzles/tile),
// m/l/alpha are per-lane scalars. exp2 domain (QSCALE folded into q).
// Only the diagonal tile is masked (exactly one per q-tile, wave-uniform).
// ---------------------------------------------------------------------------
__global__ __launch_bounds__(256)
void attn_kernel(const __bf16* __restrict__ qb,
                 const __bf16* __restrict__ kb,
                 const __bf16* __restrict__ vt,
                 float* __restrict__ out) {
  __shared__ __align__(16) __bf16 pA[4][16][72];   // row stride 144B (16B-aligned)
  __shared__ float ml_m[4][16];
  __shared__ float ml_l[4][16];
  __shared__ float olds[4][16][64];

  const int tid   = threadIdx.x;
  const int wv    = tid >> 6;
  const int lane  = tid & 63;
  const int ln    = lane & 15;
  const int quad  = lane >> 4;
  const int b     = blockIdx.y;

  const __bf16* Q = qb + (size_t)b * T_ * 64;
  const __bf16* K = kb + (size_t)b * T_ * 64;
  const __bf16* V = vt + (size_t)b * 64 * T_;

#pragma unroll
  for (int qt = 0; qt < 2; qt++) {
    const int jq    = qt == 0 ? blockIdx.x : 127 - blockIdx.x;
    const int qbase = jq * 16;
    const int ntiles = (jq >> 2) + 1;       // ceil((qbase+16)/64)

    // Q as B-operand: lane ln holds q-row (qbase+ln), k-slice quad*8..+7
    bf16x8 qa0 = *(const bf16x8*)(Q + (qbase + ln) * 64 + quad * 8);
    bf16x8 qa1 = *(const bf16x8*)(Q + (qbase + ln) * 64 + 32 + quad * 8);

    f32x4 acc[4] = {};
    float m_i = -INFINITY, l_i = 0.f;       // per-lane: q-row = qbase + ln

    bf16x8 kfa[4], kfb[4], vfa[4], vfb[4];
    if (wv < ntiles) {
#pragma unroll
      for (int h = 0; h < 4; h++) {
        const __bf16* kr = K + (size_t)(wv * 64 + h * 16 + ln) * 64 + quad * 8;
        kfa[h] = *(const bf16x8*)kr;
        kfb[h] = *(const bf16x8*)(kr + 32);
      }
    }

    for (int jt = wv; jt < ntiles; jt += 4) {
      const int kv0 = jt * 64;

      // S^T = K Q^T : row = kv (kv0 + h*16 + quad*4 + r), col = q-row (ln)
      f32x4 s[4] = {};
#pragma unroll
      for (int h = 0; h < 4; h++) {
        s[h] = __builtin_amdgcn_mfma_f32_16x16x32_bf16(kfa[h], qa0, s[h], 0, 0, 0);
        s[h] = __builtin_amdgcn_mfma_f32_16x16x32_bf16(kfb[h], qa1, s[h], 0, 0, 0);
      }

      // prefetch next K tile (regs dead after QK)
      if (jt + 4 < ntiles) {
#pragma unroll
        for (int h = 0; h < 4; h++) {
          const __bf16* kr = K + (size_t)(kv0 + 256 + h * 16 + ln) * 64 + quad * 8;
          kfa[h] = *(const bf16x8*)kr;
          kfb[h] = *(const bf16x8*)(kr + 32);
        }
      }
      // current tile's V — latency hides under softmax
#pragma unroll
      for (int nt = 0; nt < 4; nt++) {
        const __bf16* vr = V + (size_t)(nt * 16 + ln) * T_ + kv0 + quad * 8;
        vfa[nt] = *(const bf16x8*)vr;
        vfb[nt] = *(const bf16x8*)(vr + 32);
      }

      // mask: only the diagonal tile (exactly one per q-tile)
      if (kv0 + 63 > qbase) {
        const int lim = qbase + ln - kv0 - quad * 4;   // valid iff h*16+r <= lim
#pragma unroll
        for (int h = 0; h < 4; h++)
#pragma unroll
          for (int r = 0; r < 4; r++)
            if (h * 16 + r > lim) s[h][r] = -INFINITY;
      }

      // row max: 15 in-lane + 2 shuffle rounds (across quads)
      float mx = s[0][0];
#pragma unroll
      for (int h = 0; h < 4; h++)
#pragma unroll
        for (int r = 0; r < 4; r++) mx = fmaxf(mx, s[h][r]);
      mx = fmaxf(mx, __shfl_xor(mx, 16));
      mx = fmaxf(mx, __shfl_xor(mx, 32));

      float mnew = fmaxf(m_i, mx);
      float alpha = __builtin_amdgcn_exp2f(m_i - mnew);
      m_i = mnew;

      float p[4][4], sm = 0.f;
#pragma unroll
      for (int h = 0; h < 4; h++)
#pragma unroll
        for (int r = 0; r < 4; r++) {
          p[h][r] = __builtin_amdgcn_exp2f(s[h][r] - mnew);
          sm += p[h][r];
        }
      sm += __shfl_xor(sm, 16);
      sm += __shfl_xor(sm, 32);
      l_i = l_i * alpha + sm;

      // rescale acc: acc rows are q-rows quad*4+r -> fetch their alphas
      float ar[4];
#pragma unroll
      for (int r = 0; r < 4; r++) ar[r] = __shfl(alpha, quad * 4 + r);
#pragma unroll
      for (int nt = 0; nt < 4; nt++)
#pragma unroll
        for (int r = 0; r < 4; r++) acc[nt][r] *= ar[r];

      // P (transposed store): lane's q-row = ln, kv cols h*16+quad*4+0..3
#pragma unroll
      for (int h = 0; h < 4; h++) {
        bf16x4 pk;
#pragma unroll
        for (int r = 0; r < 4; r++) pk[r] = (__bf16)p[h][r];
        *(bf16x4*)(&pA[wv][ln][h * 16 + quad * 4]) = pk;   // ds_write_b64
      }

      // A-frag read (within-wave RAW; compiler inserts lgkmcnt)
      bf16x8 pa0 = *(const bf16x8*)(&pA[wv][ln][quad * 8]);
      bf16x8 pa1 = *(const bf16x8*)(&pA[wv][ln][32 + quad * 8]);
#pragma unroll
      for (int nt = 0; nt < 4; nt++) {
        acc[nt] = __builtin_amdgcn_mfma_f32_16x16x32_bf16(pa0, vfa[nt], acc[nt], 0, 0, 0);
        acc[nt] = __builtin_amdgcn_mfma_f32_16x16x32_bf16(pa1, vfb[nt], acc[nt], 0, 0, 0);
      }
    }

    // --- merge the 4 waves' partial (m, l, O) ---
    __syncthreads();                       // guard ml/olds reuse across qt
    if (quad == 0) {
      ml_m[wv][ln] = m_i;
      ml_l[wv][ln] = l_i;
    }
    __syncthreads();

#pragma unroll
    for (int r = 0; r < 4; r++) {
      int row = quad * 4 + r;
      float mstar = fmaxf(fmaxf(ml_m[0][row], ml_m[1][row]),
                          fmaxf(ml_m[2][row], ml_m[3][row]));
      float factor = __builtin_amdgcn_exp2f(ml_m[wv][row] - mstar);
#pragma unroll
      for (int nt = 0; nt < 4; nt++)
        olds[wv][row][nt * 16 + ln] = acc[nt][r] * factor;
    }
    __syncthreads();

    {
      int row = tid >> 4;
      int h0 = (tid & 15) * 4;
      float mstar = fmaxf(fmaxf(ml_m[0][row], ml_m[1][row]),
                          fmaxf(ml_m[2][row], ml_m[3][row]));
      float ltot = 0.f;
#pragma unroll
      for (int w = 0; w < 4; w++)
        ltot += ml_l[w][row] * __builtin_amdgcn_exp2f(ml_m[w][row] - mstar);
      float inv = 1.0f / ltot;
      float4 o = {0.f, 0.f, 0.f, 0.f};
#pragma unroll
      for (int w = 0; w < 4; w++) {
        float4 t = *(const float4*)(&olds[w][row][h0]);
        o.x += t.x; o.y += t.y; o.z += t.z; o.w += t.w;
      }
      o.x *= inv; o.y *= inv; o.z *= inv; o.w *= inv;
      *(float4*)(out + ((size_t)(b * T_ + qbase + row)) * 64 + h0) = o;
    }
  }
}

// ---------------------------------------------------------------------------
extern "C" void kernel_launch(void* const* d_in, const int* in_sizes, int n_in,
                              void* d_out, int out_size, void* d_ws, size_t ws_size,
                              hipStream_t stream) {
  const float* x  = (const float*)d_in[0];
  const float* Wk = (const float*)d_in[1];
  const float* bk = (const float*)d_in[2];
  const float* Wq = (const float*)d_in[3];
  const float* bq = (const float*)d_in[4];
  const float* Wv = (const float*)d_in[5];
  const float* bv = (const float*)d_in[6];
  float* out = (float*)d_out;

  char* ws = (char*)d_ws;
  __bf16* qb = (__bf16*)(ws);                                  // 2 MB (pre-scaled)
  __bf16* kb = (__bf16*)(ws + (size_t)2 * 1024 * 1024);        // 2 MB
  __bf16* vt = (__bf16*)(ws + (size_t)4 * 1024 * 1024);        // 2 MB (transposed)
  __bf16* Wt = (__bf16*)(ws + (size_t)6 * 1024 * 1024);        // 384 KB

  castw_kernel<<<dim3(16, 3), 256, 0, stream>>>(Wq, Wk, Wv, Wt);
  proj_kernel<<<512, 256, 0, stream>>>(x, Wt, bq, bk, bv, qb, kb, vt);
  attn_kernel<<<dim3(64, 8), 256, 0, stream>>>(qb, kb, vt, out);
}

// Round 6
// 146.339 us; speedup vs baseline: 1.5298x; 1.1036x over previous
//
#include <hip/hip_runtime.h>
#include <hip/hip_bf16.h>
#include <cmath>

#define B_ 8
#define T_ 2048
#define D_ 1024
#define H_ 64

typedef __bf16 bf16x8 __attribute__((ext_vector_type(8)));
typedef __bf16 bf16x4 __attribute__((ext_vector_type(4)));
typedef float f32x4 __attribute__((ext_vector_type(4)));

// q scaled by 1/sqrt(64) * log2(e) so softmax runs in exp2 domain
#define QSCALE 0.18033688011112042f

// async global->LDS, 16B per lane, lands at (wave-uniform lds base) + lane*16
__device__ __forceinline__ void async_copy16(const void* g, void* lds) {
  __builtin_amdgcn_global_load_lds(
      (const __attribute__((address_space(1))) unsigned int*)g,
      (__attribute__((address_space(3))) unsigned int*)lds,
      16, 0, 0);
}

// ---------------------------------------------------------------------------
// Kernel 1: cast + transpose weights via LDS: Wt[mat][h=64][d=1024] bf16
// ---------------------------------------------------------------------------
__global__ __launch_bounds__(256)
void castw_kernel(const float* __restrict__ w0,
                  const float* __restrict__ w1,
                  const float* __restrict__ w2,
                  __bf16* __restrict__ Wt) {
  __shared__ float tile[64][65];
  const int mat = blockIdx.y;
  const float* w = (mat == 0) ? w0 : (mat == 1) ? w1 : w2;
  const int d0 = blockIdx.x * 64;
  const int t = threadIdx.x;
#pragma unroll
  for (int i = 0; i < 16; i++) {
    int idx = i * 256 + t;
    int dl = idx >> 6, h = idx & 63;
    tile[dl][h] = w[(size_t)(d0 + dl) * 64 + h];
  }
  __syncthreads();
  const int h = t >> 2;
  const int dc = (t & 3) * 16;
  bf16x8 o0, o1;
#pragma unroll
  for (int j = 0; j < 8; j++) {
    o0[j] = (__bf16)tile[dc + j][h];
    o1[j] = (__bf16)tile[dc + 8 + j][h];
  }
  bf16x8* dst = (bf16x8*)(Wt + (size_t)mat * 65536 + (size_t)h * 1024 + d0 + dc);
  dst[0] = o0;
  dst[1] = o1;
}

// ---------------------------------------------------------------------------
// Kernel 2: fused QKV projection. grid 512, block 256, M=32/block, N=192,
// K in 8 slices of 128 (v5: 16 slices of 64 -> halved barrier count, doubled
// compute per drain). LDS image is XOR-swizzled *through the async copy's
// per-lane global address* (dst must stay contiguous): source k-chunk =
// chunk ^ (row&15). Fragment reads apply the same XOR -> <=2-way bank access
// (v5 had 16-way on B reads: 2.36M SQ_LDS_BANK_CONFLICT).
// ---------------------------------------------------------------------------
__global__ __launch_bounds__(256)
void proj_kernel(const float* __restrict__ x,
                 const __bf16* __restrict__ Wt,
                 const float* __restrict__ bq,
                 const float* __restrict__ bk,
                 const float* __restrict__ bv,
                 __bf16* __restrict__ qb,
                 __bf16* __restrict__ kb,
                 __bf16* __restrict__ vt) {
  __shared__ __align__(16) __bf16 xs[32 * 128];    // 8 KB, swizzled image
  __shared__ __align__(16) __bf16 wsl[192 * 128];  // 48 KB, swizzled image

  const int tid  = threadIdx.x;
  const int wv   = tid >> 6;
  const int lane = tid & 63;
  const int ln   = lane & 15;
  const int quad = lane >> 4;
  const int m0   = blockIdx.x * 32;

  f32x4 acc[6] = {};                 // [mt*3 + nt]

  for (int s = 0; s < 8; s++) {
    const int k0 = s * 128;
    __syncthreads();                 // prior slice's readers done

    // ---- stage W: 12 async 1KB copies per wave (48 total). Instr i covers
    // rows i*4..i*4+3 x 128 k. Lane l -> LDS chunk (l>>4 row, l&15 pos);
    // source chunk kc = (l&15) ^ (row&15) makes the LDS image swizzled.
#pragma unroll
    for (int j = 0; j < 12; j++) {
      int i = wv * 12 + j;
      int grow = i * 4 + (lane >> 4);
      int kc = (lane & 15) ^ (grow & 15);
      const __bf16* gp = Wt + (size_t)grow * 1024 + k0 + kc * 8;
      async_copy16(gp, wsl + i * 512);
    }

    // ---- stage x: 32 rows x 128 k, coalesced fp32 -> bf16 -> swizzled LDS
#pragma unroll
    for (int u = 0; u < 2; u++)
#pragma unroll
      for (int kh = 0; kh < 2; kh++) {
        int row = (tid >> 4) + u * 16;
        int fi = (tid & 15) + kh * 16;           // float4 index 0..31
        float4 f = *(const float4*)(x + (size_t)(m0 + row) * D_ + k0 + fi * 4);
        bf16x4 hv;
        hv[0] = (__bf16)f.x; hv[1] = (__bf16)f.y;
        hv[2] = (__bf16)f.z; hv[3] = (__bf16)f.w;
        int ch = fi >> 1, half = fi & 1;
        *(bf16x4*)(xs + row * 128 + ((ch ^ (row & 15)) * 8) + half * 4) = hv;
      }

    __syncthreads();                 // drains vmcnt (async W) + lgkm (x)

    // ---- compute: 24 MFMAs per wave per slice ----
#pragma unroll
    for (int ks = 0; ks < 4; ks++) {
      bf16x8 af[2];
#pragma unroll
      for (int mt = 0; mt < 2; mt++) {
        int m = mt * 16 + ln;
        af[mt] = *(const bf16x8*)(xs + m * 128 + (((ks * 4 + quad) ^ (m & 15)) * 8));
      }
#pragma unroll
      for (int nt = 0; nt < 3; nt++) {
        int col = wv * 48 + nt * 16 + ln;
        bf16x8 bf = *(const bf16x8*)(wsl + col * 128 + (((ks * 4 + quad) ^ (col & 15)) * 8));
#pragma unroll
        for (int mt = 0; mt < 2; mt++)
          acc[mt * 3 + nt] =
              __builtin_amdgcn_mfma_f32_16x16x32_bf16(af[mt], bf, acc[mt * 3 + nt], 0, 0, 0);
      }
    }
  }

  // ---- epilogue: bias + store (q pre-scaled by QSCALE for exp2 softmax) ----
#pragma unroll
  for (int nt = 0; nt < 3; nt++) {
    int idx = wv * 48 + nt * 16;
    int mat = idx >> 6;
    int h = (idx & 63) + ln;
    float bcol = ((mat == 0) ? bq : (mat == 1) ? bk : bv)[h];
#pragma unroll
    for (int mt = 0; mt < 2; mt++) {
      f32x4 a = acc[mt * 3 + nt];
      int grow0 = m0 + mt * 16 + quad * 4;
      if (mat == 0) {
#pragma unroll
        for (int r = 0; r < 4; r++)
          qb[(size_t)(grow0 + r) * 64 + h] = (__bf16)((a[r] + bcol) * QSCALE);
      } else if (mat == 1) {
#pragma unroll
        for (int r = 0; r < 4; r++)
          kb[(size_t)(grow0 + r) * 64 + h] = (__bf16)(a[r] + bcol);
      } else {
        int bb = grow0 >> 11, t0 = grow0 & 2047;
        bf16x4 pv;
#pragma unroll
        for (int r = 0; r < 4; r++)
          pv[r] = (__bf16)(a[r] + bcol);
        *(bf16x4*)(vt + (size_t)(bb * 64 + h) * T_ + t0) = pv;
      }
    }
  }
}

// ---------------------------------------------------------------------------
// Kernel 3: causal flash attention (UNCHANGED from v5 so its counters surface
// in the next profile). Balanced q-tile pairs {j,127-j}, transposed scores,
// exp2 domain, diagonal-only masking.
// ---------------------------------------------------------------------------
__global__ __launch_bounds__(256)
void attn_kernel(const __bf16* __restrict__ qb,
                 const __bf16* __restrict__ kb,
                 const __bf16* __restrict__ vt,
                 float* __restrict__ out) {
  __shared__ __align__(16) __bf16 pA[4][16][72];
  __shared__ float ml_m[4][16];
  __shared__ float ml_l[4][16];
  __shared__ float olds[4][16][64];

  const int tid   = threadIdx.x;
  const int wv    = tid >> 6;
  const int lane  = tid & 63;
  const int ln    = lane & 15;
  const int quad  = lane >> 4;
  const int b     = blockIdx.y;

  const __bf16* Q = qb + (size_t)b * T_ * 64;
  const __bf16* K = kb + (size_t)b * T_ * 64;
  const __bf16* V = vt + (size_t)b * 64 * T_;

#pragma unroll
  for (int qt = 0; qt < 2; qt++) {
    const int jq    = qt == 0 ? blockIdx.x : 127 - blockIdx.x;
    const int qbase = jq * 16;
    const int ntiles = (jq >> 2) + 1;

    bf16x8 qa0 = *(const bf16x8*)(Q + (qbase + ln) * 64 + quad * 8);
    bf16x8 qa1 = *(const bf16x8*)(Q + (qbase + ln) * 64 + 32 + quad * 8);

    f32x4 acc[4] = {};
    float m_i = -INFINITY, l_i = 0.f;

    bf16x8 kfa[4], kfb[4], vfa[4], vfb[4];
    if (wv < ntiles) {
#pragma unroll
      for (int h = 0; h < 4; h++) {
        const __bf16* kr = K + (size_t)(wv * 64 + h * 16 + ln) * 64 + quad * 8;
        kfa[h] = *(const bf16x8*)kr;
        kfb[h] = *(const bf16x8*)(kr + 32);
      }
    }

    for (int jt = wv; jt < ntiles; jt += 4) {
      const int kv0 = jt * 64;

      f32x4 s[4] = {};
#pragma unroll
      for (int h = 0; h < 4; h++) {
        s[h] = __builtin_amdgcn_mfma_f32_16x16x32_bf16(kfa[h], qa0, s[h], 0, 0, 0);
        s[h] = __builtin_amdgcn_mfma_f32_16x16x32_bf16(kfb[h], qa1, s[h], 0, 0, 0);
      }

      if (jt + 4 < ntiles) {
#pragma unroll
        for (int h = 0; h < 4; h++) {
          const __bf16* kr = K + (size_t)(kv0 + 256 + h * 16 + ln) * 64 + quad * 8;
          kfa[h] = *(const bf16x8*)kr;
          kfb[h] = *(const bf16x8*)(kr + 32);
        }
      }
#pragma unroll
      for (int nt = 0; nt < 4; nt++) {
        const __bf16* vr = V + (size_t)(nt * 16 + ln) * T_ + kv0 + quad * 8;
        vfa[nt] = *(const bf16x8*)vr;
        vfb[nt] = *(const bf16x8*)(vr + 32);
      }

      if (kv0 + 63 > qbase) {
        const int lim = qbase + ln - kv0 - quad * 4;
#pragma unroll
        for (int h = 0; h < 4; h++)
#pragma unroll
          for (int r = 0; r < 4; r++)
            if (h * 16 + r > lim) s[h][r] = -INFINITY;
      }

      float mx = s[0][0];
#pragma unroll
      for (int h = 0; h < 4; h++)
#pragma unroll
        for (int r = 0; r < 4; r++) mx = fmaxf(mx, s[h][r]);
      mx = fmaxf(mx, __shfl_xor(mx, 16));
      mx = fmaxf(mx, __shfl_xor(mx, 32));

      float mnew = fmaxf(m_i, mx);
      float alpha = __builtin_amdgcn_exp2f(m_i - mnew);
      m_i = mnew;

      float p[4][4], sm = 0.f;
#pragma unroll
      for (int h = 0; h < 4; h++)
#pragma unroll
        for (int r = 0; r < 4; r++) {
          p[h][r] = __builtin_amdgcn_exp2f(s[h][r] - mnew);
          sm += p[h][r];
        }
      sm += __shfl_xor(sm, 16);
      sm += __shfl_xor(sm, 32);
      l_i = l_i * alpha + sm;

      float ar[4];
#pragma unroll
      for (int r = 0; r < 4; r++) ar[r] = __shfl(alpha, quad * 4 + r);
#pragma unroll
      for (int nt = 0; nt < 4; nt++)
#pragma unroll
        for (int r = 0; r < 4; r++) acc[nt][r] *= ar[r];

#pragma unroll
      for (int h = 0; h < 4; h++) {
        bf16x4 pk;
#pragma unroll
        for (int r = 0; r < 4; r++) pk[r] = (__bf16)p[h][r];
        *(bf16x4*)(&pA[wv][ln][h * 16 + quad * 4]) = pk;
      }

      bf16x8 pa0 = *(const bf16x8*)(&pA[wv][ln][quad * 8]);
      bf16x8 pa1 = *(const bf16x8*)(&pA[wv][ln][32 + quad * 8]);
#pragma unroll
      for (int nt = 0; nt < 4; nt++) {
        acc[nt] = __builtin_amdgcn_mfma_f32_16x16x32_bf16(pa0, vfa[nt], acc[nt], 0, 0, 0);
        acc[nt] = __builtin_amdgcn_mfma_f32_16x16x32_bf16(pa1, vfb[nt], acc[nt], 0, 0, 0);
      }
    }

    __syncthreads();
    if (quad == 0) {
      ml_m[wv][ln] = m_i;
      ml_l[wv][ln] = l_i;
    }
    __syncthreads();

#pragma unroll
    for (int r = 0; r < 4; r++) {
      int row = quad * 4 + r;
      float mstar = fmaxf(fmaxf(ml_m[0][row], ml_m[1][row]),
                          fmaxf(ml_m[2][row], ml_m[3][row]));
      float factor = __builtin_amdgcn_exp2f(ml_m[wv][row] - mstar);
#pragma unroll
      for (int nt = 0; nt < 4; nt++)
        olds[wv][row][nt * 16 + ln] = acc[nt][r] * factor;
    }
    __syncthreads();

    {
      int row = tid >> 4;
      int h0 = (tid & 15) * 4;
      float mstar = fmaxf(fmaxf(ml_m[0][row], ml_m[1][row]),
                          fmaxf(ml_m[2][row], ml_m[3][row]));
      float ltot = 0.f;
#pragma unroll
      for (int w = 0; w < 4; w++)
        ltot += ml_l[w][row] * __builtin_amdgcn_exp2f(ml_m[w][row] - mstar);
      float inv = 1.0f / ltot;
      float4 o = {0.f, 0.f, 0.f, 0.f};
#pragma unroll
      for (int w = 0; w < 4; w++) {
        float4 t = *(const float4*)(&olds[w][row][h0]);
        o.x += t.x; o.y += t.y; o.z += t.z; o.w += t.w;
      }
      o.x *= inv; o.y *= inv; o.z *= inv; o.w *= inv;
      *(float4*)(out + ((size_t)(b * T_ + qbase + row)) * 64 + h0) = o;
    }
  }
}

// ---------------------------------------------------------------------------
extern "C" void kernel_launch(void* const* d_in, const int* in_sizes, int n_in,
                              void* d_out, int out_size, void* d_ws, size_t ws_size,
                              hipStream_t stream) {
  const float* x  = (const float*)d_in[0];
  const float* Wk = (const float*)d_in[1];
  const float* bk = (const float*)d_in[2];
  const float* Wq = (const float*)d_in[3];
  const float* bq = (const float*)d_in[4];
  const float* Wv = (const float*)d_in[5];
  const float* bv = (const float*)d_in[6];
  float* out = (float*)d_out;

  char* ws = (char*)d_ws;
  __bf16* qb = (__bf16*)(ws);                                  // 2 MB (pre-scaled)
  __bf16* kb = (__bf16*)(ws + (size_t)2 * 1024 * 1024);        // 2 MB
  __bf16* vt = (__bf16*)(ws + (size_t)4 * 1024 * 1024);        // 2 MB (transposed)
  __bf16* Wt = (__bf16*)(ws + (size_t)6 * 1024 * 1024);        // 384 KB

  castw_kernel<<<dim3(16, 3), 256, 0, stream>>>(Wq, Wk, Wv, Wt);
  proj_kernel<<<512, 256, 0, stream>>>(x, Wt, bq, bk, bv, qb, kb, vt);
  attn_kernel<<<dim3(64, 8), 256, 0, stream>>>(qb, kb, vt, out);
}

// Round 7
// 140.867 us; speedup vs baseline: 1.5893x; 1.0388x over previous
//
#include <hip/hip_runtime.h>
#include <hip/hip_bf16.h>
#include <cmath>

#define B_ 8
#define T_ 2048
#define D_ 1024
#define H_ 64

typedef __bf16 bf16x8 __attribute__((ext_vector_type(8)));
typedef __bf16 bf16x4 __attribute__((ext_vector_type(4)));
typedef float f32x4 __attribute__((ext_vector_type(4)));

// q scaled by 1/sqrt(64) * log2(e) so softmax runs in exp2 domain
#define QSCALE 0.18033688011112042f

// async global->LDS, 16B per lane, lands at (wave-uniform lds base) + lane*16
__device__ __forceinline__ void async_copy16(const void* g, void* lds) {
  __builtin_amdgcn_global_load_lds(
      (const __attribute__((address_space(1))) unsigned int*)g,
      (__attribute__((address_space(3))) unsigned int*)lds,
      16, 0, 0);
}

// ---------------------------------------------------------------------------
// Kernel 1: cast + transpose weights via LDS: Wt[mat][h=64][d=1024] bf16
// ---------------------------------------------------------------------------
__global__ __launch_bounds__(256)
void castw_kernel(const float* __restrict__ w0,
                  const float* __restrict__ w1,
                  const float* __restrict__ w2,
                  __bf16* __restrict__ Wt) {
  __shared__ float tile[64][65];
  const int mat = blockIdx.y;
  const float* w = (mat == 0) ? w0 : (mat == 1) ? w1 : w2;
  const int d0 = blockIdx.x * 64;
  const int t = threadIdx.x;
#pragma unroll
  for (int i = 0; i < 16; i++) {
    int idx = i * 256 + t;
    int dl = idx >> 6, h = idx & 63;
    tile[dl][h] = w[(size_t)(d0 + dl) * 64 + h];
  }
  __syncthreads();
  const int h = t >> 2;
  const int dc = (t & 3) * 16;
  bf16x8 o0, o1;
#pragma unroll
  for (int j = 0; j < 8; j++) {
    o0[j] = (__bf16)tile[dc + j][h];
    o1[j] = (__bf16)tile[dc + 8 + j][h];
  }
  bf16x8* dst = (bf16x8*)(Wt + (size_t)mat * 65536 + (size_t)h * 1024 + d0 + dc);
  dst[0] = o0;
  dst[1] = o1;
}

// ---------------------------------------------------------------------------
// Kernel 2: fused QKV projection (UNCHANGED from v6). grid 512, block 256,
// M=32/block, N=192, K in 8 slices of 128, XOR-swizzled async staging.
// ---------------------------------------------------------------------------
__global__ __launch_bounds__(256)
void proj_kernel(const float* __restrict__ x,
                 const __bf16* __restrict__ Wt,
                 const float* __restrict__ bq,
                 const float* __restrict__ bk,
                 const float* __restrict__ bv,
                 __bf16* __restrict__ qb,
                 __bf16* __restrict__ kb,
                 __bf16* __restrict__ vt) {
  __shared__ __align__(16) __bf16 xs[32 * 128];
  __shared__ __align__(16) __bf16 wsl[192 * 128];

  const int tid  = threadIdx.x;
  const int wv   = tid >> 6;
  const int lane = tid & 63;
  const int ln   = lane & 15;
  const int quad = lane >> 4;
  const int m0   = blockIdx.x * 32;

  f32x4 acc[6] = {};

  for (int s = 0; s < 8; s++) {
    const int k0 = s * 128;
    __syncthreads();

#pragma unroll
    for (int j = 0; j < 12; j++) {
      int i = wv * 12 + j;
      int grow = i * 4 + (lane >> 4);
      int kc = (lane & 15) ^ (grow & 15);
      const __bf16* gp = Wt + (size_t)grow * 1024 + k0 + kc * 8;
      async_copy16(gp, wsl + i * 512);
    }

#pragma unroll
    for (int u = 0; u < 2; u++)
#pragma unroll
      for (int kh = 0; kh < 2; kh++) {
        int row = (tid >> 4) + u * 16;
        int fi = (tid & 15) + kh * 16;
        float4 f = *(const float4*)(x + (size_t)(m0 + row) * D_ + k0 + fi * 4);
        bf16x4 hv;
        hv[0] = (__bf16)f.x; hv[1] = (__bf16)f.y;
        hv[2] = (__bf16)f.z; hv[3] = (__bf16)f.w;
        int ch = fi >> 1, half = fi & 1;
        *(bf16x4*)(xs + row * 128 + ((ch ^ (row & 15)) * 8) + half * 4) = hv;
      }

    __syncthreads();

#pragma unroll
    for (int ks = 0; ks < 4; ks++) {
      bf16x8 af[2];
#pragma unroll
      for (int mt = 0; mt < 2; mt++) {
        int m = mt * 16 + ln;
        af[mt] = *(const bf16x8*)(xs + m * 128 + (((ks * 4 + quad) ^ (m & 15)) * 8));
      }
#pragma unroll
      for (int nt = 0; nt < 3; nt++) {
        int col = wv * 48 + nt * 16 + ln;
        bf16x8 bf = *(const bf16x8*)(wsl + col * 128 + (((ks * 4 + quad) ^ (col & 15)) * 8));
#pragma unroll
        for (int mt = 0; mt < 2; mt++)
          acc[mt * 3 + nt] =
              __builtin_amdgcn_mfma_f32_16x16x32_bf16(af[mt], bf, acc[mt * 3 + nt], 0, 0, 0);
      }
    }
  }

#pragma unroll
  for (int nt = 0; nt < 3; nt++) {
    int idx = wv * 48 + nt * 16;
    int mat = idx >> 6;
    int h = (idx & 63) + ln;
    float bcol = ((mat == 0) ? bq : (mat == 1) ? bk : bv)[h];
#pragma unroll
    for (int mt = 0; mt < 2; mt++) {
      f32x4 a = acc[mt * 3 + nt];
      int grow0 = m0 + mt * 16 + quad * 4;
      if (mat == 0) {
#pragma unroll
        for (int r = 0; r < 4; r++)
          qb[(size_t)(grow0 + r) * 64 + h] = (__bf16)((a[r] + bcol) * QSCALE);
      } else if (mat == 1) {
#pragma unroll
        for (int r = 0; r < 4; r++)
          kb[(size_t)(grow0 + r) * 64 + h] = (__bf16)(a[r] + bcol);
      } else {
        int bb = grow0 >> 11, t0 = grow0 & 2047;
        bf16x4 pv;
#pragma unroll
        for (int r = 0; r < 4; r++)
          pv[r] = (__bf16)(a[r] + bcol);
        *(bf16x4*)(vt + (size_t)(bb * 64 + h) * T_ + t0) = pv;
      }
    }
  }
}

// ---------------------------------------------------------------------------
// Kernel 3: causal flash attention, DUAL q-tile per block.
// grid (64,8), block 256. Block handles q-tiles {p, 127-p} CONCURRENTLY:
// phase 1 (kv tiles in the low tile's range): one K/V fragment set feeds both
// q-tiles' QK+PV -> K/V traffic ~halved, and the two independent softmax
// chains interleave (2x ILP on the serial chain). Phase 2: high tile only.
// Iters/block: 33 -> ntH (17..32). Dispatch balancing: round-1 blocks (by<4)
// take p=63-bx (light blocks finish first), round-2 p=bx (heavy first in
// queue) -> early finishers pick up heavy blocks, ~uniform CU totals.
// ---------------------------------------------------------------------------
__global__ __launch_bounds__(256)
void attn_kernel(const __bf16* __restrict__ qb,
                 const __bf16* __restrict__ kb,
                 const __bf16* __restrict__ vt,
                 float* __restrict__ out) {
  __shared__ __align__(16) __bf16 pA[2][4][16][72];  // [lo/hi][wave][row][col]
  __shared__ float ml_m[4][16];
  __shared__ float ml_l[4][16];
  __shared__ float olds[4][16][64];

  const int tid   = threadIdx.x;
  const int wv    = tid >> 6;
  const int lane  = tid & 63;
  const int ln    = lane & 15;
  const int quad  = lane >> 4;
  const int b     = blockIdx.y;

  const int p     = ((blockIdx.y >> 2) & 1) ? blockIdx.x : 63 - blockIdx.x;
  const int jqL   = p, jqH = 127 - p;
  const int qbL   = jqL * 16, qbH = jqH * 16;
  const int ntL   = (jqL >> 2) + 1;
  const int ntH   = (jqH >> 2) + 1;

  const __bf16* Q = qb + (size_t)b * T_ * 64;
  const __bf16* K = kb + (size_t)b * T_ * 64;
  const __bf16* V = vt + (size_t)b * 64 * T_;

  bf16x8 qaL0 = *(const bf16x8*)(Q + (qbL + ln) * 64 + quad * 8);
  bf16x8 qaL1 = *(const bf16x8*)(Q + (qbL + ln) * 64 + 32 + quad * 8);
  bf16x8 qaH0 = *(const bf16x8*)(Q + (qbH + ln) * 64 + quad * 8);
  bf16x8 qaH1 = *(const bf16x8*)(Q + (qbH + ln) * 64 + 32 + quad * 8);

  f32x4 accL[4] = {}, accH[4] = {};
  float mL = -INFINITY, lL = 0.f, mH = -INFINITY, lH = 0.f;

  bf16x8 kfa[4], kfb[4], vfa[4], vfb[4];
#pragma unroll
  for (int h = 0; h < 4; h++) {
    const __bf16* kr = K + (size_t)(wv * 64 + h * 16 + ln) * 64 + quad * 8;
    kfa[h] = *(const bf16x8*)kr;
    kfb[h] = *(const bf16x8*)(kr + 32);
  }

  int jt = wv;

  // ---- phase 1: both q-tiles share K/V fragments ----
  for (; jt < ntL; jt += 4) {
    const int kv0 = jt * 64;

    f32x4 sH[4] = {}, sL[4] = {};
#pragma unroll
    for (int h = 0; h < 4; h++) {
      sH[h] = __builtin_amdgcn_mfma_f32_16x16x32_bf16(kfa[h], qaH0, sH[h], 0, 0, 0);
      sH[h] = __builtin_amdgcn_mfma_f32_16x16x32_bf16(kfb[h], qaH1, sH[h], 0, 0, 0);
      sL[h] = __builtin_amdgcn_mfma_f32_16x16x32_bf16(kfa[h], qaL0, sL[h], 0, 0, 0);
      sL[h] = __builtin_amdgcn_mfma_f32_16x16x32_bf16(kfb[h], qaL1, sL[h], 0, 0, 0);
    }

    if (jt + 4 < ntH) {
#pragma unroll
      for (int h = 0; h < 4; h++) {
        const __bf16* kr = K + (size_t)(kv0 + 256 + h * 16 + ln) * 64 + quad * 8;
        kfa[h] = *(const bf16x8*)kr;
        kfb[h] = *(const bf16x8*)(kr + 32);
      }
    }
#pragma unroll
    for (int nt = 0; nt < 4; nt++) {
      const __bf16* vr = V + (size_t)(nt * 16 + ln) * T_ + kv0 + quad * 8;
      vfa[nt] = *(const bf16x8*)vr;
      vfb[nt] = *(const bf16x8*)(vr + 32);
    }

    // diag mask: L's diagonal is the last phase-1 tile (H diag is in phase 2)
    if (jt == ntL - 1) {
      const int lim = qbL + ln - kv0 - quad * 4;
#pragma unroll
      for (int h = 0; h < 4; h++)
#pragma unroll
        for (int r = 0; r < 4; r++)
          if (h * 16 + r > lim) sL[h][r] = -INFINITY;
    }

    // --- two independent softmax chains (interleaved by scheduler) ---
    float mxH = sH[0][0], mxL = sL[0][0];
#pragma unroll
    for (int h = 0; h < 4; h++)
#pragma unroll
      for (int r = 0; r < 4; r++) {
        mxH = fmaxf(mxH, sH[h][r]);
        mxL = fmaxf(mxL, sL[h][r]);
      }
    mxH = fmaxf(mxH, __shfl_xor(mxH, 16));
    mxL = fmaxf(mxL, __shfl_xor(mxL, 16));
    mxH = fmaxf(mxH, __shfl_xor(mxH, 32));
    mxL = fmaxf(mxL, __shfl_xor(mxL, 32));

    float mnH = fmaxf(mH, mxH), mnL = fmaxf(mL, mxL);
    float alH = __builtin_amdgcn_exp2f(mH - mnH);
    float alL = __builtin_amdgcn_exp2f(mL - mnL);
    mH = mnH; mL = mnL;

    float pH[4][4], pL[4][4], smH = 0.f, smL = 0.f;
#pragma unroll
    for (int h = 0; h < 4; h++)
#pragma unroll
      for (int r = 0; r < 4; r++) {
        pH[h][r] = __builtin_amdgcn_exp2f(sH[h][r] - mnH);
        pL[h][r] = __builtin_amdgcn_exp2f(sL[h][r] - mnL);
        smH += pH[h][r];
        smL += pL[h][r];
      }
    smH += __shfl_xor(smH, 16);  smL += __shfl_xor(smL, 16);
    smH += __shfl_xor(smH, 32);  smL += __shfl_xor(smL, 32);
    lH = lH * alH + smH;
    lL = lL * alL + smL;

    float arH[4], arL[4];
#pragma unroll
    for (int r = 0; r < 4; r++) {
      arH[r] = __shfl(alH, quad * 4 + r);
      arL[r] = __shfl(alL, quad * 4 + r);
    }
#pragma unroll
    for (int nt = 0; nt < 4; nt++)
#pragma unroll
      for (int r = 0; r < 4; r++) {
        accH[nt][r] *= arH[r];
        accL[nt][r] *= arL[r];
      }

#pragma unroll
    for (int h = 0; h < 4; h++) {
      bf16x4 ph, pl;
#pragma unroll
      for (int r = 0; r < 4; r++) { ph[r] = (__bf16)pH[h][r]; pl[r] = (__bf16)pL[h][r]; }
      *(bf16x4*)(&pA[1][wv][ln][h * 16 + quad * 4]) = ph;
      *(bf16x4*)(&pA[0][wv][ln][h * 16 + quad * 4]) = pl;
    }
    bf16x8 paH0 = *(const bf16x8*)(&pA[1][wv][ln][quad * 8]);
    bf16x8 paH1 = *(const bf16x8*)(&pA[1][wv][ln][32 + quad * 8]);
    bf16x8 paL0 = *(const bf16x8*)(&pA[0][wv][ln][quad * 8]);
    bf16x8 paL1 = *(const bf16x8*)(&pA[0][wv][ln][32 + quad * 8]);
#pragma unroll
    for (int nt = 0; nt < 4; nt++) {
      accH[nt] = __builtin_amdgcn_mfma_f32_16x16x32_bf16(paH0, vfa[nt], accH[nt], 0, 0, 0);
      accH[nt] = __builtin_amdgcn_mfma_f32_16x16x32_bf16(paH1, vfb[nt], accH[nt], 0, 0, 0);
      accL[nt] = __builtin_amdgcn_mfma_f32_16x16x32_bf16(paL0, vfa[nt], accL[nt], 0, 0, 0);
      accL[nt] = __builtin_amdgcn_mfma_f32_16x16x32_bf16(paL1, vfb[nt], accL[nt], 0, 0, 0);
    }
  }

  // ---- phase 2: high tile only ----
  for (; jt < ntH; jt += 4) {
    const int kv0 = jt * 64;

    f32x4 sH[4] = {};
#pragma unroll
    for (int h = 0; h < 4; h++) {
      sH[h] = __builtin_amdgcn_mfma_f32_16x16x32_bf16(kfa[h], qaH0, sH[h], 0, 0, 0);
      sH[h] = __builtin_amdgcn_mfma_f32_16x16x32_bf16(kfb[h], qaH1, sH[h], 0, 0, 0);
    }

    if (jt + 4 < ntH) {
#pragma unroll
      for (int h = 0; h < 4; h++) {
        const __bf16* kr = K + (size_t)(kv0 + 256 + h * 16 + ln) * 64 + quad * 8;
        kfa[h] = *(const bf16x8*)kr;
        kfb[h] = *(const bf16x8*)(kr + 32);
      }
    }
#pragma unroll
    for (int nt = 0; nt < 4; nt++) {
      const __bf16* vr = V + (size_t)(nt * 16 + ln) * T_ + kv0 + quad * 8;
      vfa[nt] = *(const bf16x8*)vr;
      vfb[nt] = *(const bf16x8*)(vr + 32);
    }

    if (jt == ntH - 1) {
      const int lim = qbH + ln - kv0 - quad * 4;
#pragma unroll
      for (int h = 0; h < 4; h++)
#pragma unroll
        for (int r = 0; r < 4; r++)
          if (h * 16 + r > lim) sH[h][r] = -INFINITY;
    }

    float mxH = sH[0][0];
#pragma unroll
    for (int h = 0; h < 4; h++)
#pragma unroll
      for (int r = 0; r < 4; r++) mxH = fmaxf(mxH, sH[h][r]);
    mxH = fmaxf(mxH, __shfl_xor(mxH, 16));
    mxH = fmaxf(mxH, __shfl_xor(mxH, 32));

    float mnH = fmaxf(mH, mxH);
    float alH = __builtin_amdgcn_exp2f(mH - mnH);
    mH = mnH;

    float pH[4][4], smH = 0.f;
#pragma unroll
    for (int h = 0; h < 4; h++)
#pragma unroll
      for (int r = 0; r < 4; r++) {
        pH[h][r] = __builtin_amdgcn_exp2f(sH[h][r] - mnH);
        smH += pH[h][r];
      }
    smH += __shfl_xor(smH, 16);
    smH += __shfl_xor(smH, 32);
    lH = lH * alH + smH;

    float arH[4];
#pragma unroll
    for (int r = 0; r < 4; r++) arH[r] = __shfl(alH, quad * 4 + r);
#pragma unroll
    for (int nt = 0; nt < 4; nt++)
#pragma unroll
      for (int r = 0; r < 4; r++) accH[nt][r] *= arH[r];

#pragma unroll
    for (int h = 0; h < 4; h++) {
      bf16x4 ph;
#pragma unroll
      for (int r = 0; r < 4; r++) ph[r] = (__bf16)pH[h][r];
      *(bf16x4*)(&pA[1][wv][ln][h * 16 + quad * 4]) = ph;
    }
    bf16x8 paH0 = *(const bf16x8*)(&pA[1][wv][ln][quad * 8]);
    bf16x8 paH1 = *(const bf16x8*)(&pA[1][wv][ln][32 + quad * 8]);
#pragma unroll
    for (int nt = 0; nt < 4; nt++) {
      accH[nt] = __builtin_amdgcn_mfma_f32_16x16x32_bf16(paH0, vfa[nt], accH[nt], 0, 0, 0);
      accH[nt] = __builtin_amdgcn_mfma_f32_16x16x32_bf16(paH1, vfb[nt], accH[nt], 0, 0, 0);
    }
  }

  // ---- merge + store: low tile, then high tile (sequential LDS reuse) ----
#pragma unroll
  for (int side = 0; side < 2; side++) {
    const float m_i = side == 0 ? mL : mH;
    const float l_i = side == 0 ? lL : lH;
    const f32x4* acc = side == 0 ? accL : accH;
    const int qbase  = side == 0 ? qbL : qbH;

    __syncthreads();
    if (quad == 0) {
      ml_m[wv][ln] = m_i;
      ml_l[wv][ln] = l_i;
    }
    __syncthreads();

#pragma unroll
    for (int r = 0; r < 4; r++) {
      int row = quad * 4 + r;
      float mstar = fmaxf(fmaxf(ml_m[0][row], ml_m[1][row]),
                          fmaxf(ml_m[2][row], ml_m[3][row]));
      float factor = __builtin_amdgcn_exp2f(ml_m[wv][row] - mstar);
#pragma unroll
      for (int nt = 0; nt < 4; nt++)
        olds[wv][row][nt * 16 + ln] = acc[nt][r] * factor;
    }
    __syncthreads();

    {
      int row = tid >> 4;
      int h0 = (tid & 15) * 4;
      float mstar = fmaxf(fmaxf(ml_m[0][row], ml_m[1][row]),
                          fmaxf(ml_m[2][row], ml_m[3][row]));
      float ltot = 0.f;
#pragma unroll
      for (int w = 0; w < 4; w++)
        ltot += ml_l[w][row] * __builtin_amdgcn_exp2f(ml_m[w][row] - mstar);
      float inv = 1.0f / ltot;
      float4 o = {0.f, 0.f, 0.f, 0.f};
#pragma unroll
      for (int w = 0; w < 4; w++) {
        float4 t = *(const float4*)(&olds[w][row][h0]);
        o.x += t.x; o.y += t.y; o.z += t.z; o.w += t.w;
      }
      o.x *= inv; o.y *= inv; o.z *= inv; o.w *= inv;
      *(float4*)(out + ((size_t)(b * T_ + qbase + row)) * 64 + h0) = o;
    }
  }
}

// ---------------------------------------------------------------------------
extern "C" void kernel_launch(void* const* d_in, const int* in_sizes, int n_in,
                              void* d_out, int out_size, void* d_ws, size_t ws_size,
                              hipStream_t stream) {
  const float* x  = (const float*)d_in[0];
  const float* Wk = (const float*)d_in[1];
  const float* bk = (const float*)d_in[2];
  const float* Wq = (const float*)d_in[3];
  const float* bq = (const float*)d_in[4];
  const float* Wv = (const float*)d_in[5];
  const float* bv = (const float*)d_in[6];
  float* out = (float*)d_out;

  char* ws = (char*)d_ws;
  __bf16* qb = (__bf16*)(ws);                                  // 2 MB (pre-scaled)
  __bf16* kb = (__bf16*)(ws + (size_t)2 * 1024 * 1024);        // 2 MB
  __bf16* vt = (__bf16*)(ws + (size_t)4 * 1024 * 1024);        // 2 MB (transposed)
  __bf16* Wt = (__bf16*)(ws + (size_t)6 * 1024 * 1024);        // 384 KB

  castw_kernel<<<dim3(16, 3), 256, 0, stream>>>(Wq, Wk, Wv, Wt);
  proj_kernel<<<512, 256, 0, stream>>>(x, Wt, bq, bk, bv, qb, kb, vt);
  attn_kernel<<<dim3(64, 8), 256, 0, stream>>>(qb, kb, vt, out);
}